// Round 4
// baseline (203.413 us; speedup 1.0000x reference)
//
#include <hip/hip_runtime.h>

#define B 8192
#define F 128
#define H 64

typedef __attribute__((ext_vector_type(8))) short bf16x8;
typedef __attribute__((ext_vector_type(4))) float f32x4;

static __device__ __forceinline__ unsigned short f32_to_bf16_rne(float v) {
    unsigned int u = __float_as_uint(v);
    unsigned int r = (u + 0x7FFFu + ((u >> 16) & 1u)) >> 16;
    return (unsigned short)r;
}
static __device__ __forceinline__ float bf16_to_f32(unsigned short h) {
    return __uint_as_float(((unsigned int)h) << 16);
}

// 16B-wide global->LDS DMA; LDS dest is wave-uniform base + lane*16 (linear).
#define GLOAD_LDS16(gp, lp)                                                  \
    __builtin_amdgcn_global_load_lds(                                        \
        (const __attribute__((address_space(1))) unsigned int*)(gp),         \
        (__attribute__((address_space(3))) unsigned int*)(lp), 16, 0, 0)

// Split-bf16 MFMA NAM.  Layer2 = 3x mfma_f32_16x16x32_bf16 (hh + hl + lh).
// R8: R7 passed at 107.5us ~= baseline; top-5 now shows only the harness's
// 256MiB workspace-poison fill (42.6us) -> our kernels all <42.6us.
// Back-solve says nam_main is still ~36-45us vs a ~11-15us compute floor:
// latency/residency-bound, not throughput-bound.  Changes:
//   (1) __launch_bounds__(256,4): R7's (256,3) self-capped residency
//       (measured 25% occupancy ~= 2 blocks/CU); at 80 VGPR the HW allows
//       4 blocks/CU.  More resident blocks hide each block's
//       DMA->syncthreads startup latency.
//   (2) mt loop unroll 2: lets the compiler overlap mt+1's A-prep VALU
//       with mt's MFMAs (unroll 1 forbade cross-iteration scheduling).
//   (3) Drop the xT transpose: R0's FETCH=10.8MB proved the strided
//       inputs gather is fully L2/L3-absorbed.  Prep shrinks to F=128
//       blocks (W2 table only); main reads inputs directly.
// Kept from R7: prep'd W2 hi/lo table (kills the 32x-redundant in-kernel
// RNE conversion), global_load_lds table staging, (F,B) fnn_ws full-line
// writes + nam_finish transpose/reduce, ws_size guard with R4 fallback.

// ---- prep: F blocks: W2 (H,H) f32 -> hi/lo bf16 B-fragment table ----
__global__ __launch_bounds__(256) void nam_prep(
    const float* __restrict__ W2, short* __restrict__ bhi_g,
    short* __restrict__ blo_g)
{
    const int tid = threadIdx.x;
    const int f = blockIdx.x;
    const float* W2f = W2 + (size_t)f * H * H;
    short* bhi = bhi_g + (size_t)f * 4096;
    short* blo = blo_g + (size_t)f * 4096;
#pragma unroll
    for (int t = tid; t < 512; t += 256) {
        const int n = t & 63;          // output hidden index (MFMA n)
        const int g = t >> 6;          // h-group: h = g*8 + jj (MFMA k)
        const int nt = n >> 4, c = n & 15;
        const int ks = g >> 2, q = g & 3;
        const int slot = (nt * 2 + ks) * 64 + c + 16 * q;
        bf16x8 hv, lv;
#pragma unroll
        for (int jj = 0; jj < 8; ++jj) {
            const float wv = W2f[(g * 8 + jj) * H + n];
            const unsigned short hi = f32_to_bf16_rne(wv);
            const unsigned short lo = f32_to_bf16_rne(wv - bf16_to_f32(hi));
            hv[jj] = (short)hi;
            lv[jj] = (short)lv[jj];
            lv[jj] = (short)lo;
        }
        *(bf16x8*)&bhi[slot * 8] = hv;
        *(bf16x8*)&blo[slot * 8] = lv;
    }
}

__global__ __launch_bounds__(256, 4) void nam_main(
    const float* __restrict__ inputs, const float* __restrict__ W1,
    const float* __restrict__ b1, const short* __restrict__ bhi_g,
    const short* __restrict__ blo_g, const float* __restrict__ b2,
    const float* __restrict__ W3, const float* __restrict__ b3,
    float* __restrict__ fnn_ws)
{
    const int tid = threadIdx.x;
    const int f = blockIdx.y;
    const int b0 = blockIdx.x * 256;

    const int lane = tid & 63;
    const int w    = tid >> 6;
    const int q    = lane >> 4;   // quad
    const int col  = lane & 15;

    // ---- DMA the pre-packed B-fragment slice into LDS (16KB, once) ----
    __shared__ __align__(16) short bhs[4096];   // 8 KB
    __shared__ __align__(16) short bls[4096];   // 8 KB
    {
        const short* bhi_f = bhi_g + (size_t)f * 4096;
        const short* blo_f = blo_g + (size_t)f * 4096;
#pragma unroll
        for (int c = w; c < 8; c += 4) {      // 2 chunks/table/wave
            GLOAD_LDS16(bhi_f + c * 512 + lane * 8, &bhs[c * 512]);
            GLOAD_LDS16(blo_f + c * 512 + lane * 8, &bls[c * 512]);
        }
    }

    // overlap with DMA: x gathers (strided; L2/L3-absorbed, R0-proven) +
    // per-lane weight vectors
    float x4[4];
#pragma unroll
    for (int mt = 0; mt < 4; ++mt)
        x4[mt] = inputs[(size_t)(b0 + w * 64 + mt * 16 + col) * F + f];

    const float* W1f = W1 + f * H;
    const float* b1f = b1 + f * H;
    float w1v[16], b1v[16];
#pragma unroll
    for (int ks = 0; ks < 2; ++ks)
#pragma unroll
        for (int j = 0; j < 8; ++j) {
            w1v[ks * 8 + j] = W1f[ks * 32 + q * 8 + j];
            b1v[ks * 8 + j] = b1f[ks * 32 + q * 8 + j];
        }
    const float* b2f = b2 + f * H;
    const float* W3f = W3 + f * H;
    float b2v[4], w3v[4];
#pragma unroll
    for (int nt = 0; nt < 4; ++nt) {
        b2v[nt] = b2f[nt * 16 + col];
        w3v[nt] = W3f[nt * 16 + col];
    }
    const float b3f = b3[f];

    __syncthreads();   // drains the global_load_lds DMA

    // ---- resident B fragments (LDS -> regs, once per block) ----
    bf16x8 bhi[4][2], blo[4][2];
#pragma unroll
    for (int nt = 0; nt < 4; ++nt)
#pragma unroll
        for (int ks = 0; ks < 2; ++ks) {
            const int slot = (nt * 2 + ks) * 64 + lane;
            bhi[nt][ks] = *(bf16x8*)&bhs[slot * 8];
            blo[nt][ks] = *(bf16x8*)&bls[slot * 8];
        }

    // ---- 4 m-tiles of 16 rows per wave (unroll 2: pipeline A-prep/MFMA) ----
#pragma unroll 2
    for (int mt = 0; mt < 4; ++mt) {
        const int rbase = b0 + w * 64 + mt * 16;
        const float x = x4[mt];

        f32x4 acc[4];
#pragma unroll
        for (int nt = 0; nt < 4; ++nt) {
            acc[nt][0] = b2v[nt]; acc[nt][1] = b2v[nt];
            acc[nt][2] = b2v[nt]; acc[nt][3] = b2v[nt];
        }

#pragma unroll
        for (int ks = 0; ks < 2; ++ks) {
            // A-frag: trunc-Dekker split, v_perm pair-packing.
            union { unsigned int u[4]; bf16x8 v; } Ah, Al;
#pragma unroll
            for (int t = 0; t < 4; ++t) {
                const float r0 = fmaxf(fmaf(x, w1v[ks * 8 + 2 * t],     b1v[ks * 8 + 2 * t]),     0.0f);
                const float r1 = fmaxf(fmaf(x, w1v[ks * 8 + 2 * t + 1], b1v[ks * 8 + 2 * t + 1]), 0.0f);
                const unsigned int u0 = __float_as_uint(r0);
                const unsigned int u1 = __float_as_uint(r1);
                const float l0 = r0 - __uint_as_float(u0 & 0xFFFF0000u);
                const float l1 = r1 - __uint_as_float(u1 & 0xFFFF0000u);
                Ah.u[t] = __builtin_amdgcn_perm(u1, u0, 0x07060302);
                Al.u[t] = __builtin_amdgcn_perm(__float_as_uint(l1),
                                                __float_as_uint(l0), 0x07060302);
            }
#pragma unroll
            for (int nt = 0; nt < 4; ++nt) {
                acc[nt] = __builtin_amdgcn_mfma_f32_16x16x32_bf16(Ah.v, bhi[nt][ks], acc[nt], 0, 0, 0);
                acc[nt] = __builtin_amdgcn_mfma_f32_16x16x32_bf16(Ah.v, blo[nt][ks], acc[nt], 0, 0, 0);
                acc[nt] = __builtin_amdgcn_mfma_f32_16x16x32_bf16(Al.v, bhi[nt][ks], acc[nt], 0, 0, 0);
            }
        }

        // ---- epilogue: fnn_ws[f][row] = sum_n relu(C)*W3[n] + b3 ----
        float s[4];
#pragma unroll
        for (int reg = 0; reg < 4; ++reg) {
            float t = 0.0f;
#pragma unroll
            for (int nt = 0; nt < 4; ++nt)
                t = fmaf(fmaxf(acc[nt][reg], 0.0f), w3v[nt], t);
            s[reg] = t;
        }
#pragma unroll
        for (int m_ = 1; m_ <= 8; m_ <<= 1)
#pragma unroll
            for (int reg = 0; reg < 4; ++reg)
                s[reg] += __shfl_xor(s[reg], m_, 64);
        if (col == 0) {
            // rows rbase+4q..rbase+4q+3 consecutive -> one full float4,
            // 4 lanes/wave cover a fully-written 64B line.  No atomics.
            f32x4 o;
            o[0] = s[0] + b3f; o[1] = s[1] + b3f;
            o[2] = s[2] + b3f; o[3] = s[3] + b3f;
            *(f32x4*)&fnn_ws[(size_t)f * B + rbase + 4 * q] = o;
        }
    }
}

// ---- finish: fnn_ws (F,B) -> fnn (B,F) transpose + out row-sums ----
__global__ __launch_bounds__(256) void nam_finish(
    const float* __restrict__ fnn_ws, float* __restrict__ fnn,
    float* __restrict__ out)
{
    const int tid = threadIdx.x;
    const int blk = blockIdx.x;            // 512 blocks: 128 row x 4 f chunks
    const int r0 = (blk & 127) * 64;
    const int f0 = (blk >> 7) * 32;
    __shared__ float tile[32][65];
    __shared__ float psum[4][64];

    float rsum = 0.0f;
#pragma unroll
    for (int j = 0; j < 8; ++j) {          // coalesced 256B/64-lane reads
        const int fl = j * 4 + (tid >> 6);
        const int rl = tid & 63;
        const float v = fnn_ws[(size_t)(f0 + fl) * B + r0 + rl];
        tile[fl][rl] = v;
        rsum += v;
    }
    psum[tid >> 6][tid & 63] = rsum;
    __syncthreads();
    if (tid < 64) {                        // 1 atomic per (row, f-chunk)
        const float s = psum[0][tid] + psum[1][tid] + psum[2][tid] + psum[3][tid];
        atomicAdd(&out[r0 + tid], s);
    }
#pragma unroll
    for (int j = 0; j < 8; ++j) {          // coalesced 128B/32-lane writes
        const int rl = j * 8 + (tid >> 5);
        const int fl = tid & 31;
        fnn[(size_t)(r0 + rl) * F + f0 + fl] = tile[fl][rl];
    }
}

// ---- fallback: proven R4 monolithic kernel (used only if ws too small) ----
__global__ __launch_bounds__(256, 3) void nam_mono(
    const float* __restrict__ inputs, const float* __restrict__ W1,
    const float* __restrict__ b1, const float* __restrict__ W2,
    const float* __restrict__ b2, const float* __restrict__ W3,
    const float* __restrict__ b3, float* __restrict__ out,
    float* __restrict__ fnn_out)
{
    const int tid = threadIdx.x;
    const int f = blockIdx.y;
    const int b0 = blockIdx.x * 256;

    const float* W1f = W1 + f * H;
    const float* b1f = b1 + f * H;
    const float* W2f = W2 + (size_t)f * H * H;
    const float* b2f = b2 + f * H;
    const float* W3f = W3 + f * H;

    __shared__ __align__(16) short bhi_s[512 * 8];
    __shared__ __align__(16) short blo_s[512 * 8];

#pragma unroll
    for (int t = tid; t < 512; t += 256) {
        const int n = t & 63;
        const int g = t >> 6;
        const int nt = n >> 4, c = n & 15;
        const int ks = g >> 2, q = g & 3;
        const int slot = (nt * 2 + ks) * 64 + c + 16 * q;
        bf16x8 hv, lv;
#pragma unroll
        for (int jj = 0; jj < 8; ++jj) {
            const float wv = W2f[(g * 8 + jj) * H + n];
            const unsigned short hi = f32_to_bf16_rne(wv);
            const unsigned short lo = f32_to_bf16_rne(wv - bf16_to_f32(hi));
            hv[jj] = (short)hi;
            lv[jj] = (short)lo;
        }
        *(bf16x8*)&bhi_s[slot * 8] = hv;
        *(bf16x8*)&blo_s[slot * 8] = lv;
    }

    const int lane = tid & 63;
    const int w    = tid >> 6;
    const int q    = lane >> 4;
    const int col  = lane & 15;

    float w1v[16], b1v[16];
#pragma unroll
    for (int ks = 0; ks < 2; ++ks)
#pragma unroll
        for (int j = 0; j < 8; ++j) {
            w1v[ks * 8 + j] = W1f[ks * 32 + q * 8 + j];
            b1v[ks * 8 + j] = b1f[ks * 32 + q * 8 + j];
        }
    float b2v[4], w3v[4];
#pragma unroll
    for (int nt = 0; nt < 4; ++nt) {
        b2v[nt] = b2f[nt * 16 + col];
        w3v[nt] = W3f[nt * 16 + col];
    }
    const float b3f = b3[f];

    float x4[4];
#pragma unroll
    for (int mt = 0; mt < 4; ++mt)
        x4[mt] = inputs[(size_t)(b0 + w * 64 + mt * 16 + col) * F + f];

    __syncthreads();

    bf16x8 bhi[4][2], blo[4][2];
#pragma unroll
    for (int nt = 0; nt < 4; ++nt)
#pragma unroll
        for (int ks = 0; ks < 2; ++ks) {
            const int slot = (nt * 2 + ks) * 64 + lane;
            bhi[nt][ks] = *(bf16x8*)&bhi_s[slot * 8];
            blo[nt][ks] = *(bf16x8*)&blo_s[slot * 8];
        }

#pragma unroll 1
    for (int mt = 0; mt < 4; ++mt) {
        const int rbase = b0 + w * 64 + mt * 16;
        const float x = x4[mt];

        f32x4 acc[4];
#pragma unroll
        for (int nt = 0; nt < 4; ++nt) {
            acc[nt][0] = b2v[nt]; acc[nt][1] = b2v[nt];
            acc[nt][2] = b2v[nt]; acc[nt][3] = b2v[nt];
        }

#pragma unroll
        for (int ks = 0; ks < 2; ++ks) {
            union { unsigned int u[4]; bf16x8 v; } Ah, Al;
#pragma unroll
            for (int t = 0; t < 4; ++t) {
                const float r0 = fmaxf(fmaf(x, w1v[ks * 8 + 2 * t],     b1v[ks * 8 + 2 * t]),     0.0f);
                const float r1 = fmaxf(fmaf(x, w1v[ks * 8 + 2 * t + 1], b1v[ks * 8 + 2 * t + 1]), 0.0f);
                const unsigned int u0 = __float_as_uint(r0);
                const unsigned int u1 = __float_as_uint(r1);
                const float l0 = r0 - __uint_as_float(u0 & 0xFFFF0000u);
                const float l1 = r1 - __uint_as_float(u1 & 0xFFFF0000u);
                Ah.u[t] = __builtin_amdgcn_perm(u1, u0, 0x07060302);
                Al.u[t] = __builtin_amdgcn_perm(__float_as_uint(l1),
                                                __float_as_uint(l0), 0x07060302);
            }
#pragma unroll
            for (int nt = 0; nt < 4; ++nt) {
                acc[nt] = __builtin_amdgcn_mfma_f32_16x16x32_bf16(Ah.v, bhi[nt][ks], acc[nt], 0, 0, 0);
                acc[nt] = __builtin_amdgcn_mfma_f32_16x16x32_bf16(Ah.v, blo[nt][ks], acc[nt], 0, 0, 0);
                acc[nt] = __builtin_amdgcn_mfma_f32_16x16x32_bf16(Al.v, bhi[nt][ks], acc[nt], 0, 0, 0);
            }
        }

        float s[4];
#pragma unroll
        for (int reg = 0; reg < 4; ++reg) {
            float t = 0.0f;
#pragma unroll
            for (int nt = 0; nt < 4; ++nt)
                t = fmaf(fmaxf(acc[nt][reg], 0.0f), w3v[nt], t);
            s[reg] = t;
        }
#pragma unroll
        for (int m_ = 1; m_ <= 8; m_ <<= 1)
#pragma unroll
            for (int reg = 0; reg < 4; ++reg)
                s[reg] += __shfl_xor(s[reg], m_, 64);
        if (col == 0) {
#pragma unroll
            for (int reg = 0; reg < 4; ++reg) {
                const int row = rbase + 4 * q + reg;
                const float val = s[reg] + b3f;
                fnn_out[(size_t)row * F + f] = val;
                atomicAdd(&out[row], val);
            }
        }
    }
}

extern "C" void kernel_launch(void* const* d_in, const int* in_sizes, int n_in,
                              void* d_out, int out_size, void* d_ws, size_t ws_size,
                              hipStream_t stream) {
    const float* inputs = (const float*)d_in[0];
    const float* W1     = (const float*)d_in[1];
    const float* b1     = (const float*)d_in[2];
    const float* W2     = (const float*)d_in[3];
    const float* b2     = (const float*)d_in[4];
    const float* W3     = (const float*)d_in[5];
    const float* b3     = (const float*)d_in[6];

    float* out = (float*)d_out;   // (B,)
    float* fnn = out + B;         // (B, F)

    const size_t WS_NEEDED = (size_t)F * 4096 * 2 * sizeof(short)   // tables 2MB
                           + (size_t)F * B * sizeof(float);         // fnw 4MB

    hipMemsetAsync(out, 0, B * sizeof(float), stream);

    if (ws_size >= WS_NEEDED) {
        short* bhi_g = (short*)d_ws;                        // 1 MB
        short* blo_g = bhi_g + (size_t)F * 4096;            // 1 MB
        float* fnw   = (float*)(blo_g + (size_t)F * 4096);  // 4 MB  (F, B)

        nam_prep<<<dim3(F), 256, 0, stream>>>(W2, bhi_g, blo_g);
        nam_main<<<dim3(B / 256, F), 256, 0, stream>>>(inputs, W1, b1, bhi_g,
                                                       blo_g, b2, W3, b3, fnw);
        nam_finish<<<dim3(512), 256, 0, stream>>>(fnw, fnn, out);
    } else {
        nam_mono<<<dim3(B / 256, F), 256, 0, stream>>>(inputs, W1, b1, W2, b2,
                                                       W3, b3, out, fnn);
    }
}

// Round 5
// 107.854 us; speedup vs baseline: 1.8860x; 1.8860x over previous
//
#include <hip/hip_runtime.h>

#define B 8192
#define F 128
#define H 64

typedef __attribute__((ext_vector_type(8))) short bf16x8;
typedef __attribute__((ext_vector_type(4))) float f32x4;

static __device__ __forceinline__ unsigned short f32_to_bf16_rne(float v) {
    unsigned int u = __float_as_uint(v);
    unsigned int r = (u + 0x7FFFu + ((u >> 16) & 1u)) >> 16;
    return (unsigned short)r;
}
static __device__ __forceinline__ float bf16_to_f32(unsigned short h) {
    return __uint_as_float(((unsigned int)h) << 16);
}

// 16B-wide global->LDS DMA; LDS dest is wave-uniform base + lane*16 (linear).
#define GLOAD_LDS16(gp, lp)                                                  \
    __builtin_amdgcn_global_load_lds(                                        \
        (const __attribute__((address_space(1))) unsigned int*)(gp),         \
        (__attribute__((address_space(3))) unsigned int*)(lp), 16, 0, 0)

// Split-bf16 MFMA NAM.  Layer2 = 3x mfma_f32_16x16x32_bf16 (hh + hl + lh).
// R9: R8 regressed (135us main, VGPR 64, 310MB FETCH / 184MB WRITE) with the
// IDENTICAL signature to R5.  Common factor: __launch_bounds__(256,4) -> the
// allocator targets 64 VGPR, the 16 resident B-fragments (64 VGPRs alone) no
// longer fit, and the compiler spills/rematerializes them per mt iteration.
// R0/R7 with (256,3) -> 80 VGPR, fragments resident, clean.  Twice-confirmed
// rule for this kernel: NEVER (256,4).  Changes vs R7:
//   (1) main reverted to proven (256,3) + unroll 1 + LDS table.
//   (2) grid.x 32 -> 16 (512 rows/block, 8 mt iters): halves the number of
//       blocks paying the ~2k-cycle startup (DMA -> sync -> frag loads),
//       same 89% round-efficiency (8 blocks/CU, 3 resident).
//   (3) x gather software-pipelined via scalar x_next prefetch (no
//       runtime-indexed array -> no scratch; one iteration covers the load).
//   (4) slim prep (W2 table only, from R8): R0's FETCH=10.8MB proved the
//       strided inputs gather is L2/L3-absorbed; xT transpose dropped.
// Kept: prep'd W2 hi/lo table, global_load_lds staging, (F,B) fnn_ws
// full-line writes + nam_finish, ws guard with R4-mono fallback.

// ---- prep: F blocks: W2 (H,H) f32 -> hi/lo bf16 B-fragment table ----
__global__ __launch_bounds__(256) void nam_prep(
    const float* __restrict__ W2, short* __restrict__ bhi_g,
    short* __restrict__ blo_g)
{
    const int tid = threadIdx.x;
    const int f = blockIdx.x;
    const float* W2f = W2 + (size_t)f * H * H;
    short* bhi = bhi_g + (size_t)f * 4096;
    short* blo = blo_g + (size_t)f * 4096;
#pragma unroll
    for (int t = tid; t < 512; t += 256) {
        const int n = t & 63;          // output hidden index (MFMA n)
        const int g = t >> 6;          // h-group: h = g*8 + jj (MFMA k)
        const int nt = n >> 4, c = n & 15;
        const int ks = g >> 2, q = g & 3;
        const int slot = (nt * 2 + ks) * 64 + c + 16 * q;
        bf16x8 hv, lv;
#pragma unroll
        for (int jj = 0; jj < 8; ++jj) {
            const float wv = W2f[(g * 8 + jj) * H + n];
            const unsigned short hi = f32_to_bf16_rne(wv);
            const unsigned short lo = f32_to_bf16_rne(wv - bf16_to_f32(hi));
            hv[jj] = (short)hi;
            lv[jj] = (short)lo;
        }
        *(bf16x8*)&bhi[slot * 8] = hv;
        *(bf16x8*)&blo[slot * 8] = lv;
    }
}

__global__ __launch_bounds__(256, 3) void nam_main(
    const float* __restrict__ inputs, const float* __restrict__ W1,
    const float* __restrict__ b1, const short* __restrict__ bhi_g,
    const short* __restrict__ blo_g, const float* __restrict__ b2,
    const float* __restrict__ W3, const float* __restrict__ b3,
    float* __restrict__ fnn_ws)
{
    const int tid = threadIdx.x;
    const int f = blockIdx.y;
    const int b0 = blockIdx.x * 512;   // 512 rows per block

    const int lane = tid & 63;
    const int w    = tid >> 6;
    const int q    = lane >> 4;   // quad
    const int col  = lane & 15;

    // ---- DMA the pre-packed B-fragment slice into LDS (16KB, once) ----
    __shared__ __align__(16) short bhs[4096];   // 8 KB
    __shared__ __align__(16) short bls[4096];   // 8 KB
    {
        const short* bhi_f = bhi_g + (size_t)f * 4096;
        const short* blo_f = blo_g + (size_t)f * 4096;
#pragma unroll
        for (int c = w; c < 8; c += 4) {      // 2 chunks/table/wave
            GLOAD_LDS16(bhi_f + c * 512 + lane * 8, &bhs[c * 512]);
            GLOAD_LDS16(blo_f + c * 512 + lane * 8, &bls[c * 512]);
        }
    }

    // per-lane weight vectors (L2-hot broadcasts; overlap with DMA)
    const float* W1f = W1 + f * H;
    const float* b1f = b1 + f * H;
    float w1v[16], b1v[16];
#pragma unroll
    for (int ks = 0; ks < 2; ++ks)
#pragma unroll
        for (int j = 0; j < 8; ++j) {
            w1v[ks * 8 + j] = W1f[ks * 32 + q * 8 + j];
            b1v[ks * 8 + j] = b1f[ks * 32 + q * 8 + j];
        }
    const float* b2f = b2 + f * H;
    const float* W3f = W3 + f * H;
    float b2v[4], w3v[4];
#pragma unroll
    for (int nt = 0; nt < 4; ++nt) {
        b2v[nt] = b2f[nt * 16 + col];
        w3v[nt] = W3f[nt * 16 + col];
    }
    const float b3f = b3[f];

    // first x gather (strided; L2/L3-absorbed, R0-proven)
    const int rowbase = b0 + w * 128 + col;    // wave w owns rows [w*128, w*128+128)
    float x_next = inputs[(size_t)rowbase * F + f];

    __syncthreads();   // drains the global_load_lds DMA

    // ---- resident B fragments (LDS -> regs, once per block) ----
    bf16x8 bhi[4][2], blo[4][2];
#pragma unroll
    for (int nt = 0; nt < 4; ++nt)
#pragma unroll
        for (int ks = 0; ks < 2; ++ks) {
            const int slot = (nt * 2 + ks) * 64 + lane;
            bhi[nt][ks] = *(bf16x8*)&bhs[slot * 8];
            blo[nt][ks] = *(bf16x8*)&bls[slot * 8];
        }

    // ---- 8 m-tiles of 16 rows per wave; x software-pipelined ----
#pragma unroll 1
    for (int mt = 0; mt < 8; ++mt) {
        const int rbase = b0 + w * 128 + mt * 16;
        const float x = x_next;
        if (mt < 7)   // prefetch next tile's x; covered by this iteration
            x_next = inputs[(size_t)(rowbase + (mt + 1) * 16) * F + f];

        f32x4 acc[4];
#pragma unroll
        for (int nt = 0; nt < 4; ++nt) {
            acc[nt][0] = b2v[nt]; acc[nt][1] = b2v[nt];
            acc[nt][2] = b2v[nt]; acc[nt][3] = b2v[nt];
        }

#pragma unroll
        for (int ks = 0; ks < 2; ++ks) {
            // A-frag: trunc-Dekker split, v_perm pair-packing.
            union { unsigned int u[4]; bf16x8 v; } Ah, Al;
#pragma unroll
            for (int t = 0; t < 4; ++t) {
                const float r0 = fmaxf(fmaf(x, w1v[ks * 8 + 2 * t],     b1v[ks * 8 + 2 * t]),     0.0f);
                const float r1 = fmaxf(fmaf(x, w1v[ks * 8 + 2 * t + 1], b1v[ks * 8 + 2 * t + 1]), 0.0f);
                const unsigned int u0 = __float_as_uint(r0);
                const unsigned int u1 = __float_as_uint(r1);
                const float l0 = r0 - __uint_as_float(u0 & 0xFFFF0000u);
                const float l1 = r1 - __uint_as_float(u1 & 0xFFFF0000u);
                Ah.u[t] = __builtin_amdgcn_perm(u1, u0, 0x07060302);
                Al.u[t] = __builtin_amdgcn_perm(__float_as_uint(l1),
                                                __float_as_uint(l0), 0x07060302);
            }
#pragma unroll
            for (int nt = 0; nt < 4; ++nt) {
                acc[nt] = __builtin_amdgcn_mfma_f32_16x16x32_bf16(Ah.v, bhi[nt][ks], acc[nt], 0, 0, 0);
                acc[nt] = __builtin_amdgcn_mfma_f32_16x16x32_bf16(Ah.v, blo[nt][ks], acc[nt], 0, 0, 0);
                acc[nt] = __builtin_amdgcn_mfma_f32_16x16x32_bf16(Al.v, bhi[nt][ks], acc[nt], 0, 0, 0);
            }
        }

        // ---- epilogue: fnn_ws[f][row] = sum_n relu(C)*W3[n] + b3 ----
        float s[4];
#pragma unroll
        for (int reg = 0; reg < 4; ++reg) {
            float t = 0.0f;
#pragma unroll
            for (int nt = 0; nt < 4; ++nt)
                t = fmaf(fmaxf(acc[nt][reg], 0.0f), w3v[nt], t);
            s[reg] = t;
        }
#pragma unroll
        for (int m_ = 1; m_ <= 8; m_ <<= 1)
#pragma unroll
            for (int reg = 0; reg < 4; ++reg)
                s[reg] += __shfl_xor(s[reg], m_, 64);
        if (col == 0) {
            // rows rbase+4q..rbase+4q+3 consecutive -> one full float4,
            // 4 lanes/wave cover a fully-written 64B line.  No atomics.
            f32x4 o;
            o[0] = s[0] + b3f; o[1] = s[1] + b3f;
            o[2] = s[2] + b3f; o[3] = s[3] + b3f;
            *(f32x4*)&fnn_ws[(size_t)f * B + rbase + 4 * q] = o;
        }
    }
}

// ---- finish: fnn_ws (F,B) -> fnn (B,F) transpose + out row-sums ----
__global__ __launch_bounds__(256) void nam_finish(
    const float* __restrict__ fnn_ws, float* __restrict__ fnn,
    float* __restrict__ out)
{
    const int tid = threadIdx.x;
    const int blk = blockIdx.x;            // 512 blocks: 128 row x 4 f chunks
    const int r0 = (blk & 127) * 64;
    const int f0 = (blk >> 7) * 32;
    __shared__ float tile[32][65];
    __shared__ float psum[4][64];

    float rsum = 0.0f;
#pragma unroll
    for (int j = 0; j < 8; ++j) {          // coalesced 256B/64-lane reads
        const int fl = j * 4 + (tid >> 6);
        const int rl = tid & 63;
        const float v = fnn_ws[(size_t)(f0 + fl) * B + r0 + rl];
        tile[fl][rl] = v;
        rsum += v;
    }
    psum[tid >> 6][tid & 63] = rsum;
    __syncthreads();
    if (tid < 64) {                        // 1 atomic per (row, f-chunk)
        const float s = psum[0][tid] + psum[1][tid] + psum[2][tid] + psum[3][tid];
        atomicAdd(&out[r0 + tid], s);
    }
#pragma unroll
    for (int j = 0; j < 8; ++j) {          // coalesced 128B/32-lane writes
        const int rl = j * 8 + (tid >> 5);
        const int fl = tid & 31;
        fnn[(size_t)(r0 + rl) * F + f0 + fl] = tile[fl][rl];
    }
}

// ---- fallback: proven R4 monolithic kernel (used only if ws too small) ----
__global__ __launch_bounds__(256, 3) void nam_mono(
    const float* __restrict__ inputs, const float* __restrict__ W1,
    const float* __restrict__ b1, const float* __restrict__ W2,
    const float* __restrict__ b2, const float* __restrict__ W3,
    const float* __restrict__ b3, float* __restrict__ out,
    float* __restrict__ fnn_out)
{
    const int tid = threadIdx.x;
    const int f = blockIdx.y;
    const int b0 = blockIdx.x * 256;

    const float* W1f = W1 + f * H;
    const float* b1f = b1 + f * H;
    const float* W2f = W2 + (size_t)f * H * H;
    const float* b2f = b2 + f * H;
    const float* W3f = W3 + f * H;

    __shared__ __align__(16) short bhi_s[512 * 8];
    __shared__ __align__(16) short blo_s[512 * 8];

#pragma unroll
    for (int t = tid; t < 512; t += 256) {
        const int n = t & 63;
        const int g = t >> 6;
        const int nt = n >> 4, c = n & 15;
        const int ks = g >> 2, q = g & 3;
        const int slot = (nt * 2 + ks) * 64 + c + 16 * q;
        bf16x8 hv, lv;
#pragma unroll
        for (int jj = 0; jj < 8; ++jj) {
            const float wv = W2f[(g * 8 + jj) * H + n];
            const unsigned short hi = f32_to_bf16_rne(wv);
            const unsigned short lo = f32_to_bf16_rne(wv - bf16_to_f32(hi));
            hv[jj] = (short)hi;
            lv[jj] = (short)lo;
        }
        *(bf16x8*)&bhi_s[slot * 8] = hv;
        *(bf16x8*)&blo_s[slot * 8] = lv;
    }

    const int lane = tid & 63;
    const int w    = tid >> 6;
    const int q    = lane >> 4;
    const int col  = lane & 15;

    float w1v[16], b1v[16];
#pragma unroll
    for (int ks = 0; ks < 2; ++ks)
#pragma unroll
        for (int j = 0; j < 8; ++j) {
            w1v[ks * 8 + j] = W1f[ks * 32 + q * 8 + j];
            b1v[ks * 8 + j] = b1f[ks * 32 + q * 8 + j];
        }
    float b2v[4], w3v[4];
#pragma unroll
    for (int nt = 0; nt < 4; ++nt) {
        b2v[nt] = b2f[nt * 16 + col];
        w3v[nt] = W3f[nt * 16 + col];
    }
    const float b3f = b3[f];

    float x4[4];
#pragma unroll
    for (int mt = 0; mt < 4; ++mt)
        x4[mt] = inputs[(size_t)(b0 + w * 64 + mt * 16 + col) * F + f];

    __syncthreads();

    bf16x8 bhi[4][2], blo[4][2];
#pragma unroll
    for (int nt = 0; nt < 4; ++nt)
#pragma unroll
        for (int ks = 0; ks < 2; ++ks) {
            const int slot = (nt * 2 + ks) * 64 + lane;
            bhi[nt][ks] = *(bf16x8*)&bhi_s[slot * 8];
            blo[nt][ks] = *(bf16x8*)&blo_s[slot * 8];
        }

#pragma unroll 1
    for (int mt = 0; mt < 4; ++mt) {
        const int rbase = b0 + w * 64 + mt * 16;
        const float x = x4[mt];

        f32x4 acc[4];
#pragma unroll
        for (int nt = 0; nt < 4; ++nt) {
            acc[nt][0] = b2v[nt]; acc[nt][1] = b2v[nt];
            acc[nt][2] = b2v[nt]; acc[nt][3] = b2v[nt];
        }

#pragma unroll
        for (int ks = 0; ks < 2; ++ks) {
            union { unsigned int u[4]; bf16x8 v; } Ah, Al;
#pragma unroll
            for (int t = 0; t < 4; ++t) {
                const float r0 = fmaxf(fmaf(x, w1v[ks * 8 + 2 * t],     b1v[ks * 8 + 2 * t]),     0.0f);
                const float r1 = fmaxf(fmaf(x, w1v[ks * 8 + 2 * t + 1], b1v[ks * 8 + 2 * t + 1]), 0.0f);
                const unsigned int u0 = __float_as_uint(r0);
                const unsigned int u1 = __float_as_uint(r1);
                const float l0 = r0 - __uint_as_float(u0 & 0xFFFF0000u);
                const float l1 = r1 - __uint_as_float(u1 & 0xFFFF0000u);
                Ah.u[t] = __builtin_amdgcn_perm(u1, u0, 0x07060302);
                Al.u[t] = __builtin_amdgcn_perm(__float_as_uint(l1),
                                                __float_as_uint(l0), 0x07060302);
            }
#pragma unroll
            for (int nt = 0; nt < 4; ++nt) {
                acc[nt] = __builtin_amdgcn_mfma_f32_16x16x32_bf16(Ah.v, bhi[nt][ks], acc[nt], 0, 0, 0);
                acc[nt] = __builtin_amdgcn_mfma_f32_16x16x32_bf16(Ah.v, blo[nt][ks], acc[nt], 0, 0, 0);
                acc[nt] = __builtin_amdgcn_mfma_f32_16x16x32_bf16(Al.v, bhi[nt][ks], acc[nt], 0, 0, 0);
            }
        }

        float s[4];
#pragma unroll
        for (int reg = 0; reg < 4; ++reg) {
            float t = 0.0f;
#pragma unroll
            for (int nt = 0; nt < 4; ++nt)
                t = fmaf(fmaxf(acc[nt][reg], 0.0f), w3v[nt], t);
            s[reg] = t;
        }
#pragma unroll
        for (int m_ = 1; m_ <= 8; m_ <<= 1)
#pragma unroll
            for (int reg = 0; reg < 4; ++reg)
                s[reg] += __shfl_xor(s[reg], m_, 64);
        if (col == 0) {
#pragma unroll
            for (int reg = 0; reg < 4; ++reg) {
                const int row = rbase + 4 * q + reg;
                const float val = s[reg] + b3f;
                fnn_out[(size_t)row * F + f] = val;
                atomicAdd(&out[row], val);
            }
        }
    }
}

extern "C" void kernel_launch(void* const* d_in, const int* in_sizes, int n_in,
                              void* d_out, int out_size, void* d_ws, size_t ws_size,
                              hipStream_t stream) {
    const float* inputs = (const float*)d_in[0];
    const float* W1     = (const float*)d_in[1];
    const float* b1     = (const float*)d_in[2];
    const float* W2     = (const float*)d_in[3];
    const float* b2     = (const float*)d_in[4];
    const float* W3     = (const float*)d_in[5];
    const float* b3     = (const float*)d_in[6];

    float* out = (float*)d_out;   // (B,)
    float* fnn = out + B;         // (B, F)

    const size_t WS_NEEDED = (size_t)F * 4096 * 2 * sizeof(short)   // tables 2MB
                           + (size_t)F * B * sizeof(float);         // fnw 4MB

    hipMemsetAsync(out, 0, B * sizeof(float), stream);

    if (ws_size >= WS_NEEDED) {
        short* bhi_g = (short*)d_ws;                        // 1 MB
        short* blo_g = bhi_g + (size_t)F * 4096;            // 1 MB
        float* fnw   = (float*)(blo_g + (size_t)F * 4096);  // 4 MB  (F, B)

        nam_prep<<<dim3(F), 256, 0, stream>>>(W2, bhi_g, blo_g);
        nam_main<<<dim3(B / 512, F), 256, 0, stream>>>(inputs, W1, b1, bhi_g,
                                                       blo_g, b2, W3, b3, fnw);
        nam_finish<<<dim3(512), 256, 0, stream>>>(fnw, fnn, out);
    } else {
        nam_mono<<<dim3(B / 256, F), 256, 0, stream>>>(inputs, W1, b1, W2, b2,
                                                       W3, b3, out, fnn);
    }
}

// Round 6
// 100.799 us; speedup vs baseline: 2.0180x; 1.0700x over previous
//
#include <hip/hip_runtime.h>

#define B 8192
#define F 128
#define H 64

typedef __attribute__((ext_vector_type(8))) short bf16x8;
typedef __attribute__((ext_vector_type(4))) float f32x4;

static __device__ __forceinline__ unsigned short f32_to_bf16_rne(float v) {
    unsigned int u = __float_as_uint(v);
    unsigned int r = (u + 0x7FFFu + ((u >> 16) & 1u)) >> 16;
    return (unsigned short)r;
}
static __device__ __forceinline__ float bf16_to_f32(unsigned short h) {
    return __uint_as_float(((unsigned int)h) << 16);
}

// 16B-wide global->LDS DMA; LDS dest is wave-uniform base + lane*16 (linear).
#define GLOAD_LDS16(gp, lp)                                                  \
    __builtin_amdgcn_global_load_lds(                                        \
        (const __attribute__((address_space(1))) unsigned int*)(gp),         \
        (__attribute__((address_space(3))) unsigned int*)(lp), 16, 0, 0)

// Split-bf16 MFMA NAM.  Layer2 = 3x mfma_f32_16x16x32_bf16 (hh + hl + lh).
// R10: R9 gave clean traffic (FETCH 10.8MB, WRITE 4MB, VGPR 80) but main
// is still 41.4us at 21% Mfma / 37.5% VALU -> ~40% stall.  The per-mt
// epilogue is the culprit: 16 __shfl_xor = a 4-deep dependent lgkm chain
// (~200+cyc) serializing the tail of every mt, plus ~3 VALU per shfl.
// Fix: per-mt, lanes scatter their 4 W3-folded partials into a per-wave
// LDS tile [128][18] (pad 18 -> <=2-way bank conflicts, free per m136);
// fire-and-forget, no chain.  One reduce at kernel end per wave: 32
// conflict-free ds_read_b32 + 30 adds + two fully-coalesced 256B stores.
// LDS 52KB/block -> still exactly 3 blocks/CU.  nam_finish reshaped to
// 128 full-F blocks: 'out' becomes a plain store (no atomics) and the
// hipMemsetAsync dispatch is dropped from the fast path.
// Hard rules kept: __launch_bounds__(256,3) ONLY ((256,4) -> 64-VGPR
// spill catastrophe, twice measured); LDS table via global_load_lds;
// grid (16,F) with x_next prefetch; ws guard with R4-mono fallback.

// ---- prep: F blocks: W2 (H,H) f32 -> hi/lo bf16 B-fragment table ----
__global__ __launch_bounds__(256) void nam_prep(
    const float* __restrict__ W2, short* __restrict__ bhi_g,
    short* __restrict__ blo_g)
{
    const int tid = threadIdx.x;
    const int f = blockIdx.x;
    const float* W2f = W2 + (size_t)f * H * H;
    short* bhi = bhi_g + (size_t)f * 4096;
    short* blo = blo_g + (size_t)f * 4096;
#pragma unroll
    for (int t = tid; t < 512; t += 256) {
        const int n = t & 63;          // output hidden index (MFMA n)
        const int g = t >> 6;          // h-group: h = g*8 + jj (MFMA k)
        const int nt = n >> 4, c = n & 15;
        const int ks = g >> 2, q = g & 3;
        const int slot = (nt * 2 + ks) * 64 + c + 16 * q;
        bf16x8 hv, lv;
#pragma unroll
        for (int jj = 0; jj < 8; ++jj) {
            const float wv = W2f[(g * 8 + jj) * H + n];
            const unsigned short hi = f32_to_bf16_rne(wv);
            const unsigned short lo = f32_to_bf16_rne(wv - bf16_to_f32(hi));
            hv[jj] = (short)hi;
            lv[jj] = (short)lo;
        }
        *(bf16x8*)&bhi[slot * 8] = hv;
        *(bf16x8*)&blo[slot * 8] = lv;
    }
}

__global__ __launch_bounds__(256, 3) void nam_main(
    const float* __restrict__ inputs, const float* __restrict__ W1,
    const float* __restrict__ b1, const short* __restrict__ bhi_g,
    const short* __restrict__ blo_g, const float* __restrict__ b2,
    const float* __restrict__ W3, const float* __restrict__ b3,
    float* __restrict__ fnn_ws)
{
    const int tid = threadIdx.x;
    const int f = blockIdx.y;
    const int b0 = blockIdx.x * 512;   // 512 rows per block

    const int lane = tid & 63;
    const int w    = tid >> 6;
    const int q    = lane >> 4;   // quad
    const int col  = lane & 15;

    // per-wave partial-sum tile: rows = local row (mt*16+4q+reg), 16 cols,
    // pad to 18 f32 (72B) -> writes/reads <=2-way bank aliasing (free).
    __shared__ float s_tile[4][128][18];        // 36864 B
    __shared__ __align__(16) short bhs[4096];   // 8 KB
    __shared__ __align__(16) short bls[4096];   // 8 KB

    // ---- DMA the pre-packed B-fragment slice into LDS (16KB, once) ----
    {
        const short* bhi_f = bhi_g + (size_t)f * 4096;
        const short* blo_f = blo_g + (size_t)f * 4096;
#pragma unroll
        for (int c = w; c < 8; c += 4) {      // 2 chunks/table/wave
            GLOAD_LDS16(bhi_f + c * 512 + lane * 8, &bhs[c * 512]);
            GLOAD_LDS16(blo_f + c * 512 + lane * 8, &bls[c * 512]);
        }
    }

    // per-lane weight vectors (L2-hot broadcasts; overlap with DMA)
    const float* W1f = W1 + f * H;
    const float* b1f = b1 + f * H;
    float w1v[16], b1v[16];
#pragma unroll
    for (int ks = 0; ks < 2; ++ks)
#pragma unroll
        for (int j = 0; j < 8; ++j) {
            w1v[ks * 8 + j] = W1f[ks * 32 + q * 8 + j];
            b1v[ks * 8 + j] = b1f[ks * 32 + q * 8 + j];
        }
    const float* b2f = b2 + f * H;
    const float* W3f = W3 + f * H;
    float b2v[4], w3v[4];
#pragma unroll
    for (int nt = 0; nt < 4; ++nt) {
        b2v[nt] = b2f[nt * 16 + col];
        w3v[nt] = W3f[nt * 16 + col];
    }
    const float b3f = b3[f];

    // first x gather (strided; L2/L3-absorbed, R0-proven)
    const int rowbase = b0 + w * 128 + col;    // wave w owns rows [w*128, +128)
    float x_next = inputs[(size_t)rowbase * F + f];

    __syncthreads();   // drains the global_load_lds DMA

    // ---- resident B fragments (LDS -> regs, once per block) ----
    bf16x8 bhi[4][2], blo[4][2];
#pragma unroll
    for (int nt = 0; nt < 4; ++nt)
#pragma unroll
        for (int ks = 0; ks < 2; ++ks) {
            const int slot = (nt * 2 + ks) * 64 + lane;
            bhi[nt][ks] = *(bf16x8*)&bhs[slot * 8];
            blo[nt][ks] = *(bf16x8*)&bls[slot * 8];
        }

    // ---- 8 m-tiles of 16 rows per wave; x software-pipelined ----
#pragma unroll 1
    for (int mt = 0; mt < 8; ++mt) {
        const float x = x_next;
        if (mt < 7)   // prefetch next tile's x; covered by this iteration
            x_next = inputs[(size_t)(rowbase + (mt + 1) * 16) * F + f];

        f32x4 acc[4];
#pragma unroll
        for (int nt = 0; nt < 4; ++nt) {
            acc[nt][0] = b2v[nt]; acc[nt][1] = b2v[nt];
            acc[nt][2] = b2v[nt]; acc[nt][3] = b2v[nt];
        }

#pragma unroll
        for (int ks = 0; ks < 2; ++ks) {
            // A-frag: trunc-Dekker split, v_perm pair-packing.
            union { unsigned int u[4]; bf16x8 v; } Ah, Al;
#pragma unroll
            for (int t = 0; t < 4; ++t) {
                const float r0 = fmaxf(fmaf(x, w1v[ks * 8 + 2 * t],     b1v[ks * 8 + 2 * t]),     0.0f);
                const float r1 = fmaxf(fmaf(x, w1v[ks * 8 + 2 * t + 1], b1v[ks * 8 + 2 * t + 1]), 0.0f);
                const unsigned int u0 = __float_as_uint(r0);
                const unsigned int u1 = __float_as_uint(r1);
                const float l0 = r0 - __uint_as_float(u0 & 0xFFFF0000u);
                const float l1 = r1 - __uint_as_float(u1 & 0xFFFF0000u);
                Ah.u[t] = __builtin_amdgcn_perm(u1, u0, 0x07060302);
                Al.u[t] = __builtin_amdgcn_perm(__float_as_uint(l1),
                                                __float_as_uint(l0), 0x07060302);
            }
#pragma unroll
            for (int nt = 0; nt < 4; ++nt) {
                acc[nt] = __builtin_amdgcn_mfma_f32_16x16x32_bf16(Ah.v, bhi[nt][ks], acc[nt], 0, 0, 0);
                acc[nt] = __builtin_amdgcn_mfma_f32_16x16x32_bf16(Ah.v, blo[nt][ks], acc[nt], 0, 0, 0);
                acc[nt] = __builtin_amdgcn_mfma_f32_16x16x32_bf16(Al.v, bhi[nt][ks], acc[nt], 0, 0, 0);
            }
        }

        // ---- epilogue: fold W3 and scatter partials (fire-and-forget) ----
#pragma unroll
        for (int reg = 0; reg < 4; ++reg) {
            float t = 0.0f;
#pragma unroll
            for (int nt = 0; nt < 4; ++nt)
                t = fmaf(fmaxf(acc[nt][reg], 0.0f), w3v[nt], t);
            s_tile[w][mt * 16 + 4 * q + reg][col] = t;
        }
    }

    // ---- per-wave final reduce: rows lane and lane+64; coalesced stores ----
    {
        float sum0 = 0.0f, sum1 = 0.0f;
#pragma unroll
        for (int c = 0; c < 16; ++c) {
            sum0 += s_tile[w][lane][c];
            sum1 += s_tile[w][lane + 64][c];
        }
        float* dst = fnn_ws + (size_t)f * B + b0 + w * 128;
        dst[lane]      = sum0 + b3f;
        dst[lane + 64] = sum1 + b3f;
    }
}

// ---- finish: fnn_ws (F,B) -> fnn (B,F) transpose + out row-sums ----
// 128 blocks, each handles 64 rows x all 128 features: 'out' needs no
// atomics (full sum local to block) and no prior memset.
__global__ __launch_bounds__(256) void nam_finish(
    const float* __restrict__ fnn_ws, float* __restrict__ fnn,
    float* __restrict__ out)
{
    const int tid = threadIdx.x;
    const int r0 = blockIdx.x * 64;
    __shared__ float tile[128][65];    // 33280 B
    __shared__ float psum[4][64];

    float rsum = 0.0f;
#pragma unroll
    for (int j = 0; j < 32; ++j) {     // coalesced 256B/64-lane reads
        const int fl = j * 4 + (tid >> 6);
        const int rl = tid & 63;
        const float v = fnn_ws[(size_t)fl * B + r0 + rl];
        tile[fl][rl] = v;
        rsum += v;
    }
    psum[tid >> 6][tid & 63] = rsum;
    __syncthreads();
    if (tid < 64)                      // plain store; no atomic, no memset
        out[r0 + tid] = psum[0][tid] + psum[1][tid] + psum[2][tid] + psum[3][tid];

#pragma unroll
    for (int j = 0; j < 8; ++j) {      // fnn rows: 512B-contiguous float4 writes
        const int rl = j * 8 + (tid >> 5);
        const int c4 = tid & 31;
        f32x4 v;
        v[0] = tile[c4 * 4 + 0][rl];
        v[1] = tile[c4 * 4 + 1][rl];
        v[2] = tile[c4 * 4 + 2][rl];
        v[3] = tile[c4 * 4 + 3][rl];
        *(f32x4*)&fnn[(size_t)(r0 + rl) * F + c4 * 4] = v;
    }
}

// ---- fallback: proven R4 monolithic kernel (used only if ws too small) ----
__global__ __launch_bounds__(256, 3) void nam_mono(
    const float* __restrict__ inputs, const float* __restrict__ W1,
    const float* __restrict__ b1, const float* __restrict__ W2,
    const float* __restrict__ b2, const float* __restrict__ W3,
    const float* __restrict__ b3, float* __restrict__ out,
    float* __restrict__ fnn_out)
{
    const int tid = threadIdx.x;
    const int f = blockIdx.y;
    const int b0 = blockIdx.x * 256;

    const float* W1f = W1 + f * H;
    const float* b1f = b1 + f * H;
    const float* W2f = W2 + (size_t)f * H * H;
    const float* b2f = b2 + f * H;
    const float* W3f = W3 + f * H;

    __shared__ __align__(16) short bhi_s[512 * 8];
    __shared__ __align__(16) short blo_s[512 * 8];

#pragma unroll
    for (int t = tid; t < 512; t += 256) {
        const int n = t & 63;
        const int g = t >> 6;
        const int nt = n >> 4, c = n & 15;
        const int ks = g >> 2, q = g & 3;
        const int slot = (nt * 2 + ks) * 64 + c + 16 * q;
        bf16x8 hv, lv;
#pragma unroll
        for (int jj = 0; jj < 8; ++jj) {
            const float wv = W2f[(g * 8 + jj) * H + n];
            const unsigned short hi = f32_to_bf16_rne(wv);
            const unsigned short lo = f32_to_bf16_rne(wv - bf16_to_f32(hi));
            hv[jj] = (short)hi;
            lv[jj] = (short)lo;
        }
        *(bf16x8*)&bhi_s[slot * 8] = hv;
        *(bf16x8*)&blo_s[slot * 8] = lv;
    }

    const int lane = tid & 63;
    const int w    = tid >> 6;
    const int q    = lane >> 4;
    const int col  = lane & 15;

    float w1v[16], b1v[16];
#pragma unroll
    for (int ks = 0; ks < 2; ++ks)
#pragma unroll
        for (int j = 0; j < 8; ++j) {
            w1v[ks * 8 + j] = W1f[ks * 32 + q * 8 + j];
            b1v[ks * 8 + j] = b1f[ks * 32 + q * 8 + j];
        }
    float b2v[4], w3v[4];
#pragma unroll
    for (int nt = 0; nt < 4; ++nt) {
        b2v[nt] = b2f[nt * 16 + col];
        w3v[nt] = W3f[nt * 16 + col];
    }
    const float b3f = b3[f];

    float x4[4];
#pragma unroll
    for (int mt = 0; mt < 4; ++mt)
        x4[mt] = inputs[(size_t)(b0 + w * 64 + mt * 16 + col) * F + f];

    __syncthreads();

    bf16x8 bhi[4][2], blo[4][2];
#pragma unroll
    for (int nt = 0; nt < 4; ++nt)
#pragma unroll
        for (int ks = 0; ks < 2; ++ks) {
            const int slot = (nt * 2 + ks) * 64 + lane;
            bhi[nt][ks] = *(bf16x8*)&bhi_s[slot * 8];
            blo[nt][ks] = *(bf16x8*)&blo_s[slot * 8];
        }

#pragma unroll 1
    for (int mt = 0; mt < 4; ++mt) {
        const int rbase = b0 + w * 64 + mt * 16;
        const float x = x4[mt];

        f32x4 acc[4];
#pragma unroll
        for (int nt = 0; nt < 4; ++nt) {
            acc[nt][0] = b2v[nt]; acc[nt][1] = b2v[nt];
            acc[nt][2] = b2v[nt]; acc[nt][3] = b2v[nt];
        }

#pragma unroll
        for (int ks = 0; ks < 2; ++ks) {
            union { unsigned int u[4]; bf16x8 v; } Ah, Al;
#pragma unroll
            for (int t = 0; t < 4; ++t) {
                const float r0 = fmaxf(fmaf(x, w1v[ks * 8 + 2 * t],     b1v[ks * 8 + 2 * t]),     0.0f);
                const float r1 = fmaxf(fmaf(x, w1v[ks * 8 + 2 * t + 1], b1v[ks * 8 + 2 * t + 1]), 0.0f);
                const unsigned int u0 = __float_as_uint(r0);
                const unsigned int u1 = __float_as_uint(r1);
                const float l0 = r0 - __uint_as_float(u0 & 0xFFFF0000u);
                const float l1 = r1 - __uint_as_float(u1 & 0xFFFF0000u);
                Ah.u[t] = __builtin_amdgcn_perm(u1, u0, 0x07060302);
                Al.u[t] = __builtin_amdgcn_perm(__float_as_uint(l1),
                                                __float_as_uint(l0), 0x07060302);
            }
#pragma unroll
            for (int nt = 0; nt < 4; ++nt) {
                acc[nt] = __builtin_amdgcn_mfma_f32_16x16x32_bf16(Ah.v, bhi[nt][ks], acc[nt], 0, 0, 0);
                acc[nt] = __builtin_amdgcn_mfma_f32_16x16x32_bf16(Ah.v, blo[nt][ks], acc[nt], 0, 0, 0);
                acc[nt] = __builtin_amdgcn_mfma_f32_16x16x32_bf16(Al.v, bhi[nt][ks], acc[nt], 0, 0, 0);
            }
        }

        float s[4];
#pragma unroll
        for (int reg = 0; reg < 4; ++reg) {
            float t = 0.0f;
#pragma unroll
            for (int nt = 0; nt < 4; ++nt)
                t = fmaf(fmaxf(acc[nt][reg], 0.0f), w3v[nt], t);
            s[reg] = t;
        }
#pragma unroll
        for (int m_ = 1; m_ <= 8; m_ <<= 1)
#pragma unroll
            for (int reg = 0; reg < 4; ++reg)
                s[reg] += __shfl_xor(s[reg], m_, 64);
        if (col == 0) {
#pragma unroll
            for (int reg = 0; reg < 4; ++reg) {
                const int row = rbase + 4 * q + reg;
                const float val = s[reg] + b3f;
                fnn_out[(size_t)row * F + f] = val;
                atomicAdd(&out[row], val);
            }
        }
    }
}

extern "C" void kernel_launch(void* const* d_in, const int* in_sizes, int n_in,
                              void* d_out, int out_size, void* d_ws, size_t ws_size,
                              hipStream_t stream) {
    const float* inputs = (const float*)d_in[0];
    const float* W1     = (const float*)d_in[1];
    const float* b1     = (const float*)d_in[2];
    const float* W2     = (const float*)d_in[3];
    const float* b2     = (const float*)d_in[4];
    const float* W3     = (const float*)d_in[5];
    const float* b3     = (const float*)d_in[6];

    float* out = (float*)d_out;   // (B,)
    float* fnn = out + B;         // (B, F)

    const size_t WS_NEEDED = (size_t)F * 4096 * 2 * sizeof(short)   // tables 2MB
                           + (size_t)F * B * sizeof(float);         // fnw 4MB

    if (ws_size >= WS_NEEDED) {
        short* bhi_g = (short*)d_ws;                        // 1 MB
        short* blo_g = bhi_g + (size_t)F * 4096;            // 1 MB
        float* fnw   = (float*)(blo_g + (size_t)F * 4096);  // 4 MB  (F, B)

        nam_prep<<<dim3(F), 256, 0, stream>>>(W2, bhi_g, blo_g);
        nam_main<<<dim3(B / 512, F), 256, 0, stream>>>(inputs, W1, b1, bhi_g,
                                                       blo_g, b2, W3, b3, fnw);
        nam_finish<<<dim3(128), 256, 0, stream>>>(fnw, fnn, out);
    } else {
        hipMemsetAsync(out, 0, B * sizeof(float), stream);
        nam_mono<<<dim3(B / 256, F), 256, 0, stream>>>(inputs, W1, b1, W2, b2,
                                                       W3, b3, out, fnn);
    }
}

// Round 7
// 100.333 us; speedup vs baseline: 2.0274x; 1.0046x over previous
//
#include <hip/hip_runtime.h>

#define B 8192
#define F 128
#define H 64

typedef __attribute__((ext_vector_type(8))) short bf16x8;
typedef __attribute__((ext_vector_type(4))) float f32x4;

static __device__ __forceinline__ unsigned short f32_to_bf16_rne(float v) {
    unsigned int u = __float_as_uint(v);
    unsigned int r = (u + 0x7FFFu + ((u >> 16) & 1u)) >> 16;
    return (unsigned short)r;
}
static __device__ __forceinline__ float bf16_to_f32(unsigned short h) {
    return __uint_as_float(((unsigned int)h) << 16);
}

// 16B-wide global->LDS DMA; LDS dest is wave-uniform base + lane*16 (linear).
#define GLOAD_LDS16(gp, lp)                                                  \
    __builtin_amdgcn_global_load_lds(                                        \
        (const __attribute__((address_space(1))) unsigned int*)(gp),         \
        (__attribute__((address_space(3))) unsigned int*)(lp), 16, 0, 0)

// Split-bf16 MFMA NAM.  Layer2 = 3x mfma_f32_16x16x32_bf16 (hh + hl + lh).
// R11: R10 was a WIN (107.9 -> 100.8; main ~35us, out of top-5).  R9's
// counters showed OccupancyPercent 21.5% -- residency is LDS-capped:
// s_tile 36.8KB + tables 16KB = 52.8KB -> only 3 blocks/CU, and the
// lockstep waves can't cover the ~40% stall fraction.  Single change this
// round: s_tile halved to [4][64][18] (18.4KB; total 34.8KB -> 4
// blocks/CU, +33% resident waves) with the per-wave reduce run twice
// (after mt=3 and mt=7, 64 rows each).  Numerics bit-identical: same
// partials, same 16-col ascending add order.  Same-wave LDS
// write->read->rewrite ordering is compiler-enforced; no barrier needed.
// Hard rules kept: __launch_bounds__(256,3) ONLY ((256,4) -> 64-VGPR
// spill catastrophe, twice measured); LDS table via global_load_lds
// (linear dest); grid (16,F) with x_next prefetch; fire-and-forget LDS
// scatter epilogue (no shfl chains); ws guard with R4-mono fallback.

// ---- prep: F blocks: W2 (H,H) f32 -> hi/lo bf16 B-fragment table ----
__global__ __launch_bounds__(256) void nam_prep(
    const float* __restrict__ W2, short* __restrict__ bhi_g,
    short* __restrict__ blo_g)
{
    const int tid = threadIdx.x;
    const int f = blockIdx.x;
    const float* W2f = W2 + (size_t)f * H * H;
    short* bhi = bhi_g + (size_t)f * 4096;
    short* blo = blo_g + (size_t)f * 4096;
#pragma unroll
    for (int t = tid; t < 512; t += 256) {
        const int n = t & 63;          // output hidden index (MFMA n)
        const int g = t >> 6;          // h-group: h = g*8 + jj (MFMA k)
        const int nt = n >> 4, c = n & 15;
        const int ks = g >> 2, q = g & 3;
        const int slot = (nt * 2 + ks) * 64 + c + 16 * q;
        bf16x8 hv, lv;
#pragma unroll
        for (int jj = 0; jj < 8; ++jj) {
            const float wv = W2f[(g * 8 + jj) * H + n];
            const unsigned short hi = f32_to_bf16_rne(wv);
            const unsigned short lo = f32_to_bf16_rne(wv - bf16_to_f32(hi));
            hv[jj] = (short)hi;
            lv[jj] = (short)lo;
        }
        *(bf16x8*)&bhi[slot * 8] = hv;
        *(bf16x8*)&blo[slot * 8] = lv;
    }
}

__global__ __launch_bounds__(256, 3) void nam_main(
    const float* __restrict__ inputs, const float* __restrict__ W1,
    const float* __restrict__ b1, const short* __restrict__ bhi_g,
    const short* __restrict__ blo_g, const float* __restrict__ b2,
    const float* __restrict__ W3, const float* __restrict__ b3,
    float* __restrict__ fnn_ws)
{
    const int tid = threadIdx.x;
    const int f = blockIdx.y;
    const int b0 = blockIdx.x * 512;   // 512 rows per block

    const int lane = tid & 63;
    const int w    = tid >> 6;
    const int q    = lane >> 4;   // quad
    const int col  = lane & 15;

    // per-wave partial-sum tile, HALF-sized (64 rows): row = (mt&3)*16+4q+reg,
    // 16 cols, pad to 18 f32 -> <=2-way bank aliasing (free).  Reduced and
    // reused after mt=3 and mt=7.  Total LDS 34.8KB -> 4 blocks/CU.
    __shared__ float s_tile[4][64][18];         // 18432 B
    __shared__ __align__(16) short bhs[4096];   // 8 KB
    __shared__ __align__(16) short bls[4096];   // 8 KB

    // ---- DMA the pre-packed B-fragment slice into LDS (16KB, once) ----
    {
        const short* bhi_f = bhi_g + (size_t)f * 4096;
        const short* blo_f = blo_g + (size_t)f * 4096;
#pragma unroll
        for (int c = w; c < 8; c += 4) {      // 2 chunks/table/wave
            GLOAD_LDS16(bhi_f + c * 512 + lane * 8, &bhs[c * 512]);
            GLOAD_LDS16(blo_f + c * 512 + lane * 8, &bls[c * 512]);
        }
    }

    // per-lane weight vectors (L2-hot broadcasts; overlap with DMA)
    const float* W1f = W1 + f * H;
    const float* b1f = b1 + f * H;
    float w1v[16], b1v[16];
#pragma unroll
    for (int ks = 0; ks < 2; ++ks)
#pragma unroll
        for (int j = 0; j < 8; ++j) {
            w1v[ks * 8 + j] = W1f[ks * 32 + q * 8 + j];
            b1v[ks * 8 + j] = b1f[ks * 32 + q * 8 + j];
        }
    const float* b2f = b2 + f * H;
    const float* W3f = W3 + f * H;
    float b2v[4], w3v[4];
#pragma unroll
    for (int nt = 0; nt < 4; ++nt) {
        b2v[nt] = b2f[nt * 16 + col];
        w3v[nt] = W3f[nt * 16 + col];
    }
    const float b3f = b3[f];

    // first x gather (strided; L2/L3-absorbed, R0-proven)
    const int rowbase = b0 + w * 128 + col;    // wave w owns rows [w*128, +128)
    float x_next = inputs[(size_t)rowbase * F + f];

    __syncthreads();   // drains the global_load_lds DMA

    // ---- resident B fragments (LDS -> regs, once per block) ----
    bf16x8 bhi[4][2], blo[4][2];
#pragma unroll
    for (int nt = 0; nt < 4; ++nt)
#pragma unroll
        for (int ks = 0; ks < 2; ++ks) {
            const int slot = (nt * 2 + ks) * 64 + lane;
            bhi[nt][ks] = *(bf16x8*)&bhs[slot * 8];
            blo[nt][ks] = *(bf16x8*)&bls[slot * 8];
        }

    // ---- 8 m-tiles of 16 rows per wave; x software-pipelined ----
#pragma unroll 1
    for (int mt = 0; mt < 8; ++mt) {
        const float x = x_next;
        if (mt < 7)   // prefetch next tile's x; covered by this iteration
            x_next = inputs[(size_t)(rowbase + (mt + 1) * 16) * F + f];

        f32x4 acc[4];
#pragma unroll
        for (int nt = 0; nt < 4; ++nt) {
            acc[nt][0] = b2v[nt]; acc[nt][1] = b2v[nt];
            acc[nt][2] = b2v[nt]; acc[nt][3] = b2v[nt];
        }

#pragma unroll
        for (int ks = 0; ks < 2; ++ks) {
            // A-frag: trunc-Dekker split, v_perm pair-packing.
            union { unsigned int u[4]; bf16x8 v; } Ah, Al;
#pragma unroll
            for (int t = 0; t < 4; ++t) {
                const float r0 = fmaxf(fmaf(x, w1v[ks * 8 + 2 * t],     b1v[ks * 8 + 2 * t]),     0.0f);
                const float r1 = fmaxf(fmaf(x, w1v[ks * 8 + 2 * t + 1], b1v[ks * 8 + 2 * t + 1]), 0.0f);
                const unsigned int u0 = __float_as_uint(r0);
                const unsigned int u1 = __float_as_uint(r1);
                const float l0 = r0 - __uint_as_float(u0 & 0xFFFF0000u);
                const float l1 = r1 - __uint_as_float(u1 & 0xFFFF0000u);
                Ah.u[t] = __builtin_amdgcn_perm(u1, u0, 0x07060302);
                Al.u[t] = __builtin_amdgcn_perm(__float_as_uint(l1),
                                                __float_as_uint(l0), 0x07060302);
            }
#pragma unroll
            for (int nt = 0; nt < 4; ++nt) {
                acc[nt] = __builtin_amdgcn_mfma_f32_16x16x32_bf16(Ah.v, bhi[nt][ks], acc[nt], 0, 0, 0);
                acc[nt] = __builtin_amdgcn_mfma_f32_16x16x32_bf16(Ah.v, blo[nt][ks], acc[nt], 0, 0, 0);
                acc[nt] = __builtin_amdgcn_mfma_f32_16x16x32_bf16(Al.v, bhi[nt][ks], acc[nt], 0, 0, 0);
            }
        }

        // ---- epilogue: fold W3 and scatter partials (fire-and-forget) ----
#pragma unroll
        for (int reg = 0; reg < 4; ++reg) {
            float t = 0.0f;
#pragma unroll
            for (int nt = 0; nt < 4; ++nt)
                t = fmaf(fmaxf(acc[nt][reg], 0.0f), w3v[nt], t);
            s_tile[w][(mt & 3) * 16 + 4 * q + reg][col] = t;
        }

        // ---- per-half reduce: 64 rows, 1 row/lane; coalesced 256B store ----
        if ((mt & 3) == 3) {
            float sum = 0.0f;
#pragma unroll
            for (int c = 0; c < 16; ++c)
                sum += s_tile[w][lane][c];
            float* dst = fnn_ws + (size_t)f * B + b0 + w * 128 + (mt >> 2) * 64;
            dst[lane] = sum + b3f;
        }
    }
}

// ---- finish: fnn_ws (F,B) -> fnn (B,F) transpose + out row-sums ----
// 128 blocks, each handles 64 rows x all 128 features: 'out' needs no
// atomics (full sum local to block) and no prior memset.
__global__ __launch_bounds__(256) void nam_finish(
    const float* __restrict__ fnn_ws, float* __restrict__ fnn,
    float* __restrict__ out)
{
    const int tid = threadIdx.x;
    const int r0 = blockIdx.x * 64;
    __shared__ float tile[128][65];    // 33280 B
    __shared__ float psum[4][64];

    float rsum = 0.0f;
#pragma unroll
    for (int j = 0; j < 32; ++j) {     // coalesced 256B/64-lane reads
        const int fl = j * 4 + (tid >> 6);
        const int rl = tid & 63;
        const float v = fnn_ws[(size_t)fl * B + r0 + rl];
        tile[fl][rl] = v;
        rsum += v;
    }
    psum[tid >> 6][tid & 63] = rsum;
    __syncthreads();
    if (tid < 64)                      // plain store; no atomic, no memset
        out[r0 + tid] = psum[0][tid] + psum[1][tid] + psum[2][tid] + psum[3][tid];

#pragma unroll
    for (int j = 0; j < 8; ++j) {      // fnn rows: 512B-contiguous float4 writes
        const int rl = j * 8 + (tid >> 5);
        const int c4 = tid & 31;
        f32x4 v;
        v[0] = tile[c4 * 4 + 0][rl];
        v[1] = tile[c4 * 4 + 1][rl];
        v[2] = tile[c4 * 4 + 2][rl];
        v[3] = tile[c4 * 4 + 3][rl];
        *(f32x4*)&fnn[(size_t)(r0 + rl) * F + c4 * 4] = v;
    }
}

// ---- fallback: proven R4 monolithic kernel (used only if ws too small) ----
__global__ __launch_bounds__(256, 3) void nam_mono(
    const float* __restrict__ inputs, const float* __restrict__ W1,
    const float* __restrict__ b1, const float* __restrict__ W2,
    const float* __restrict__ b2, const float* __restrict__ W3,
    const float* __restrict__ b3, float* __restrict__ out,
    float* __restrict__ fnn_out)
{
    const int tid = threadIdx.x;
    const int f = blockIdx.y;
    const int b0 = blockIdx.x * 256;

    const float* W1f = W1 + f * H;
    const float* b1f = b1 + f * H;
    const float* W2f = W2 + (size_t)f * H * H;
    const float* b2f = b2 + f * H;
    const float* W3f = W3 + f * H;

    __shared__ __align__(16) short bhi_s[512 * 8];
    __shared__ __align__(16) short blo_s[512 * 8];

#pragma unroll
    for (int t = tid; t < 512; t += 256) {
        const int n = t & 63;
        const int g = t >> 6;
        const int nt = n >> 4, c = n & 15;
        const int ks = g >> 2, q = g & 3;
        const int slot = (nt * 2 + ks) * 64 + c + 16 * q;
        bf16x8 hv, lv;
#pragma unroll
        for (int jj = 0; jj < 8; ++jj) {
            const float wv = W2f[(g * 8 + jj) * H + n];
            const unsigned short hi = f32_to_bf16_rne(wv);
            const unsigned short lo = f32_to_bf16_rne(wv - bf16_to_f32(hi));
            hv[jj] = (short)hi;
            lv[jj] = (short)lo;
        }
        *(bf16x8*)&bhi_s[slot * 8] = hv;
        *(bf16x8*)&blo_s[slot * 8] = lv;
    }

    const int lane = tid & 63;
    const int w    = tid >> 6;
    const int q    = lane >> 4;
    const int col  = lane & 15;

    float w1v[16], b1v[16];
#pragma unroll
    for (int ks = 0; ks < 2; ++ks)
#pragma unroll
        for (int j = 0; j < 8; ++j) {
            w1v[ks * 8 + j] = W1f[ks * 32 + q * 8 + j];
            b1v[ks * 8 + j] = b1f[ks * 32 + q * 8 + j];
        }
    float b2v[4], w3v[4];
#pragma unroll
    for (int nt = 0; nt < 4; ++nt) {
        b2v[nt] = b2f[nt * 16 + col];
        w3v[nt] = W3f[nt * 16 + col];
    }
    const float b3f = b3[f];

    float x4[4];
#pragma unroll
    for (int mt = 0; mt < 4; ++mt)
        x4[mt] = inputs[(size_t)(b0 + w * 64 + mt * 16 + col) * F + f];

    __syncthreads();

    bf16x8 bhi[4][2], blo[4][2];
#pragma unroll
    for (int nt = 0; nt < 4; ++nt)
#pragma unroll
        for (int ks = 0; ks < 2; ++ks) {
            const int slot = (nt * 2 + ks) * 64 + lane;
            bhi[nt][ks] = *(bf16x8*)&bhi_s[slot * 8];
            blo[nt][ks] = *(bf16x8*)&blo_s[slot * 8];
        }

#pragma unroll 1
    for (int mt = 0; mt < 4; ++mt) {
        const int rbase = b0 + w * 64 + mt * 16;
        const float x = x4[mt];

        f32x4 acc[4];
#pragma unroll
        for (int nt = 0; nt < 4; ++nt) {
            acc[nt][0] = b2v[nt]; acc[nt][1] = b2v[nt];
            acc[nt][2] = b2v[nt]; acc[nt][3] = b2v[nt];
        }

#pragma unroll
        for (int ks = 0; ks < 2; ++ks) {
            union { unsigned int u[4]; bf16x8 v; } Ah, Al;
#pragma unroll
            for (int t = 0; t < 4; ++t) {
                const float r0 = fmaxf(fmaf(x, w1v[ks * 8 + 2 * t],     b1v[ks * 8 + 2 * t]),     0.0f);
                const float r1 = fmaxf(fmaf(x, w1v[ks * 8 + 2 * t + 1], b1v[ks * 8 + 2 * t + 1]), 0.0f);
                const unsigned int u0 = __float_as_uint(r0);
                const unsigned int u1 = __float_as_uint(r1);
                const float l0 = r0 - __uint_as_float(u0 & 0xFFFF0000u);
                const float l1 = r1 - __uint_as_float(u1 & 0xFFFF0000u);
                Ah.u[t] = __builtin_amdgcn_perm(u1, u0, 0x07060302);
                Al.u[t] = __builtin_amdgcn_perm(__float_as_uint(l1),
                                                __float_as_uint(l0), 0x07060302);
            }
#pragma unroll
            for (int nt = 0; nt < 4; ++nt) {
                acc[nt] = __builtin_amdgcn_mfma_f32_16x16x32_bf16(Ah.v, bhi[nt][ks], acc[nt], 0, 0, 0);
                acc[nt] = __builtin_amdgcn_mfma_f32_16x16x32_bf16(Ah.v, blo[nt][ks], acc[nt], 0, 0, 0);
                acc[nt] = __builtin_amdgcn_mfma_f32_16x16x32_bf16(Al.v, bhi[nt][ks], acc[nt], 0, 0, 0);
            }
        }

        float s[4];
#pragma unroll
        for (int reg = 0; reg < 4; ++reg) {
            float t = 0.0f;
#pragma unroll
            for (int nt = 0; nt < 4; ++nt)
                t = fmaf(fmaxf(acc[nt][reg], 0.0f), w3v[nt], t);
            s[reg] = t;
        }
#pragma unroll
        for (int m_ = 1; m_ <= 8; m_ <<= 1)
#pragma unroll
            for (int reg = 0; reg < 4; ++reg)
                s[reg] += __shfl_xor(s[reg], m_, 64);
        if (col == 0) {
#pragma unroll
            for (int reg = 0; reg < 4; ++reg) {
                const int row = rbase + 4 * q + reg;
                const float val = s[reg] + b3f;
                fnn_out[(size_t)row * F + f] = val;
                atomicAdd(&out[row], val);
            }
        }
    }
}

extern "C" void kernel_launch(void* const* d_in, const int* in_sizes, int n_in,
                              void* d_out, int out_size, void* d_ws, size_t ws_size,
                              hipStream_t stream) {
    const float* inputs = (const float*)d_in[0];
    const float* W1     = (const float*)d_in[1];
    const float* b1     = (const float*)d_in[2];
    const float* W2     = (const float*)d_in[3];
    const float* b2     = (const float*)d_in[4];
    const float* W3     = (const float*)d_in[5];
    const float* b3     = (const float*)d_in[6];

    float* out = (float*)d_out;   // (B,)
    float* fnn = out + B;         // (B, F)

    const size_t WS_NEEDED = (size_t)F * 4096 * 2 * sizeof(short)   // tables 2MB
                           + (size_t)F * B * sizeof(float);         // fnw 4MB

    if (ws_size >= WS_NEEDED) {
        short* bhi_g = (short*)d_ws;                        // 1 MB
        short* blo_g = bhi_g + (size_t)F * 4096;            // 1 MB
        float* fnw   = (float*)(blo_g + (size_t)F * 4096);  // 4 MB  (F, B)

        nam_prep<<<dim3(F), 256, 0, stream>>>(W2, bhi_g, blo_g);
        nam_main<<<dim3(B / 512, F), 256, 0, stream>>>(inputs, W1, b1, bhi_g,
                                                       blo_g, b2, W3, b3, fnw);
        nam_finish<<<dim3(128), 256, 0, stream>>>(fnw, fnn, out);
    } else {
        hipMemsetAsync(out, 0, B * sizeof(float), stream);
        nam_mono<<<dim3(B / 256, F), 256, 0, stream>>>(inputs, W1, b1, W2, b2,
                                                       W3, b3, out, fnn);
    }
}

// Round 8
// 99.325 us; speedup vs baseline: 2.0480x; 1.0102x over previous
//
#include <hip/hip_runtime.h>

#define B 8192
#define F 128
#define H 64

typedef __attribute__((ext_vector_type(8))) short bf16x8;
typedef __attribute__((ext_vector_type(4))) float f32x4;

static __device__ __forceinline__ unsigned short f32_to_bf16_rne(float v) {
    unsigned int u = __float_as_uint(v);
    unsigned int r = (u + 0x7FFFu + ((u >> 16) & 1u)) >> 16;
    return (unsigned short)r;
}
static __device__ __forceinline__ float bf16_to_f32(unsigned short h) {
    return __uint_as_float(((unsigned int)h) << 16);
}

// 16B-wide global->LDS DMA; LDS dest is wave-uniform base + lane*16 (linear).
#define GLOAD_LDS16(gp, lp)                                                  \
    __builtin_amdgcn_global_load_lds(                                        \
        (const __attribute__((address_space(1))) unsigned int*)(gp),         \
        (__attribute__((address_space(3))) unsigned int*)(lp), 16, 0, 0)

// Split-bf16 MFMA NAM.  Layer2 = 3x mfma_f32_16x16x32_bf16 (hh + hl + lh).
// R12: R11 (4 blocks/CU via halved s_tile) gained ~0 -> occupancy theory
// FALSIFIED: stalls are correlated across lockstep waves, not coverable by
// residency.  R9 counters (Mfma 21 + VALU 37.5, ~40% idle) localize the
// stall INSIDE the mt iteration: unroll 1 forbids overlapping mt's
// MFMA/epilogue with mt+1's A-prep, so every wave serializes
// A-prep -> 24 MFMA (4x6 dependent chains) -> epilogue, and the MFMA pipe
// idles during both VALU phases.  Single change: mt loop unroll 1 -> 2
// (NOTE: R8's unroll-2 "regression" was confounded by the (256,4) 64-VGPR
// spill catastrophe; never tested under (256,3)).  Expected VGPR ~110-130;
// abort-signal for this theory = VGPR 64 / FETCH explosion (spill).
// Hard rules kept: __launch_bounds__(256,3) ONLY ((256,4) -> spill
// catastrophe, twice measured); LDS table via global_load_lds (linear
// dest); grid (16,F) + x_next prefetch; fire-and-forget LDS scatter
// epilogue + per-half reduce (no shfl chains); ws guard + R4-mono
// fallback; no memset in fast path.

// ---- prep: F blocks: W2 (H,H) f32 -> hi/lo bf16 B-fragment table ----
__global__ __launch_bounds__(256) void nam_prep(
    const float* __restrict__ W2, short* __restrict__ bhi_g,
    short* __restrict__ blo_g)
{
    const int tid = threadIdx.x;
    const int f = blockIdx.x;
    const float* W2f = W2 + (size_t)f * H * H;
    short* bhi = bhi_g + (size_t)f * 4096;
    short* blo = blo_g + (size_t)f * 4096;
#pragma unroll
    for (int t = tid; t < 512; t += 256) {
        const int n = t & 63;          // output hidden index (MFMA n)
        const int g = t >> 6;          // h-group: h = g*8 + jj (MFMA k)
        const int nt = n >> 4, c = n & 15;
        const int ks = g >> 2, q = g & 3;
        const int slot = (nt * 2 + ks) * 64 + c + 16 * q;
        bf16x8 hv, lv;
#pragma unroll
        for (int jj = 0; jj < 8; ++jj) {
            const float wv = W2f[(g * 8 + jj) * H + n];
            const unsigned short hi = f32_to_bf16_rne(wv);
            const unsigned short lo = f32_to_bf16_rne(wv - bf16_to_f32(hi));
            hv[jj] = (short)hi;
            lv[jj] = (short)lo;
        }
        *(bf16x8*)&bhi[slot * 8] = hv;
        *(bf16x8*)&blo[slot * 8] = lv;
    }
}

__global__ __launch_bounds__(256, 3) void nam_main(
    const float* __restrict__ inputs, const float* __restrict__ W1,
    const float* __restrict__ b1, const short* __restrict__ bhi_g,
    const short* __restrict__ blo_g, const float* __restrict__ b2,
    const float* __restrict__ W3, const float* __restrict__ b3,
    float* __restrict__ fnn_ws)
{
    const int tid = threadIdx.x;
    const int f = blockIdx.y;
    const int b0 = blockIdx.x * 512;   // 512 rows per block

    const int lane = tid & 63;
    const int w    = tid >> 6;
    const int q    = lane >> 4;   // quad
    const int col  = lane & 15;

    // per-wave partial-sum tile, 64 rows: row = (mt&3)*16+4q+reg, 16 cols,
    // pad to 18 f32 -> <=2-way bank aliasing (free).  Reduced after mt=3/7.
    __shared__ float s_tile[4][64][18];         // 18432 B
    __shared__ __align__(16) short bhs[4096];   // 8 KB
    __shared__ __align__(16) short bls[4096];   // 8 KB

    // ---- DMA the pre-packed B-fragment slice into LDS (16KB, once) ----
    {
        const short* bhi_f = bhi_g + (size_t)f * 4096;
        const short* blo_f = blo_g + (size_t)f * 4096;
#pragma unroll
        for (int c = w; c < 8; c += 4) {      // 2 chunks/table/wave
            GLOAD_LDS16(bhi_f + c * 512 + lane * 8, &bhs[c * 512]);
            GLOAD_LDS16(blo_f + c * 512 + lane * 8, &bls[c * 512]);
        }
    }

    // per-lane weight vectors (L2-hot broadcasts; overlap with DMA)
    const float* W1f = W1 + f * H;
    const float* b1f = b1 + f * H;
    float w1v[16], b1v[16];
#pragma unroll
    for (int ks = 0; ks < 2; ++ks)
#pragma unroll
        for (int j = 0; j < 8; ++j) {
            w1v[ks * 8 + j] = W1f[ks * 32 + q * 8 + j];
            b1v[ks * 8 + j] = b1f[ks * 32 + q * 8 + j];
        }
    const float* b2f = b2 + f * H;
    const float* W3f = W3 + f * H;
    float b2v[4], w3v[4];
#pragma unroll
    for (int nt = 0; nt < 4; ++nt) {
        b2v[nt] = b2f[nt * 16 + col];
        w3v[nt] = W3f[nt * 16 + col];
    }
    const float b3f = b3[f];

    // first x gather (strided; L2/L3-absorbed, R0-proven)
    const int rowbase = b0 + w * 128 + col;    // wave w owns rows [w*128, +128)
    float x_next = inputs[(size_t)rowbase * F + f];

    __syncthreads();   // drains the global_load_lds DMA

    // ---- resident B fragments (LDS -> regs, once per block) ----
    bf16x8 bhi[4][2], blo[4][2];
#pragma unroll
    for (int nt = 0; nt < 4; ++nt)
#pragma unroll
        for (int ks = 0; ks < 2; ++ks) {
            const int slot = (nt * 2 + ks) * 64 + lane;
            bhi[nt][ks] = *(bf16x8*)&bhs[slot * 8];
            blo[nt][ks] = *(bf16x8*)&bls[slot * 8];
        }

    // ---- 8 m-tiles of 16 rows per wave; unroll 2 pipelines A-prep/MFMA/
    // epilogue across the mt pair (8 independent MFMA chains in flight) ----
#pragma unroll 2
    for (int mt = 0; mt < 8; ++mt) {
        const float x = x_next;
        if (mt < 7)   // prefetch next tile's x; covered by this iteration
            x_next = inputs[(size_t)(rowbase + (mt + 1) * 16) * F + f];

        f32x4 acc[4];
#pragma unroll
        for (int nt = 0; nt < 4; ++nt) {
            acc[nt][0] = b2v[nt]; acc[nt][1] = b2v[nt];
            acc[nt][2] = b2v[nt]; acc[nt][3] = b2v[nt];
        }

#pragma unroll
        for (int ks = 0; ks < 2; ++ks) {
            // A-frag: trunc-Dekker split, v_perm pair-packing.
            union { unsigned int u[4]; bf16x8 v; } Ah, Al;
#pragma unroll
            for (int t = 0; t < 4; ++t) {
                const float r0 = fmaxf(fmaf(x, w1v[ks * 8 + 2 * t],     b1v[ks * 8 + 2 * t]),     0.0f);
                const float r1 = fmaxf(fmaf(x, w1v[ks * 8 + 2 * t + 1], b1v[ks * 8 + 2 * t + 1]), 0.0f);
                const unsigned int u0 = __float_as_uint(r0);
                const unsigned int u1 = __float_as_uint(r1);
                const float l0 = r0 - __uint_as_float(u0 & 0xFFFF0000u);
                const float l1 = r1 - __uint_as_float(u1 & 0xFFFF0000u);
                Ah.u[t] = __builtin_amdgcn_perm(u1, u0, 0x07060302);
                Al.u[t] = __builtin_amdgcn_perm(__float_as_uint(l1),
                                                __float_as_uint(l0), 0x07060302);
            }
#pragma unroll
            for (int nt = 0; nt < 4; ++nt) {
                acc[nt] = __builtin_amdgcn_mfma_f32_16x16x32_bf16(Ah.v, bhi[nt][ks], acc[nt], 0, 0, 0);
                acc[nt] = __builtin_amdgcn_mfma_f32_16x16x32_bf16(Ah.v, blo[nt][ks], acc[nt], 0, 0, 0);
                acc[nt] = __builtin_amdgcn_mfma_f32_16x16x32_bf16(Al.v, bhi[nt][ks], acc[nt], 0, 0, 0);
            }
        }

        // ---- epilogue: fold W3 and scatter partials (fire-and-forget) ----
#pragma unroll
        for (int reg = 0; reg < 4; ++reg) {
            float t = 0.0f;
#pragma unroll
            for (int nt = 0; nt < 4; ++nt)
                t = fmaf(fmaxf(acc[nt][reg], 0.0f), w3v[nt], t);
            s_tile[w][(mt & 3) * 16 + 4 * q + reg][col] = t;
        }

        // ---- per-half reduce: 64 rows, 1 row/lane; coalesced 256B store ----
        if ((mt & 3) == 3) {
            float sum = 0.0f;
#pragma unroll
            for (int c = 0; c < 16; ++c)
                sum += s_tile[w][lane][c];
            float* dst = fnn_ws + (size_t)f * B + b0 + w * 128 + (mt >> 2) * 64;
            dst[lane] = sum + b3f;
        }
    }
}

// ---- finish: fnn_ws (F,B) -> fnn (B,F) transpose + out row-sums ----
// 128 blocks, each handles 64 rows x all 128 features: 'out' needs no
// atomics (full sum local to block) and no prior memset.
__global__ __launch_bounds__(256) void nam_finish(
    const float* __restrict__ fnn_ws, float* __restrict__ fnn,
    float* __restrict__ out)
{
    const int tid = threadIdx.x;
    const int r0 = blockIdx.x * 64;
    __shared__ float tile[128][65];    // 33280 B
    __shared__ float psum[4][64];

    float rsum = 0.0f;
#pragma unroll
    for (int j = 0; j < 32; ++j) {     // coalesced 256B/64-lane reads
        const int fl = j * 4 + (tid >> 6);
        const int rl = tid & 63;
        const float v = fnn_ws[(size_t)fl * B + r0 + rl];
        tile[fl][rl] = v;
        rsum += v;
    }
    psum[tid >> 6][tid & 63] = rsum;
    __syncthreads();
    if (tid < 64)                      // plain store; no atomic, no memset
        out[r0 + tid] = psum[0][tid] + psum[1][tid] + psum[2][tid] + psum[3][tid];

#pragma unroll
    for (int j = 0; j < 8; ++j) {      // fnn rows: 512B-contiguous float4 writes
        const int rl = j * 8 + (tid >> 5);
        const int c4 = tid & 31;
        f32x4 v;
        v[0] = tile[c4 * 4 + 0][rl];
        v[1] = tile[c4 * 4 + 1][rl];
        v[2] = tile[c4 * 4 + 2][rl];
        v[3] = tile[c4 * 4 + 3][rl];
        *(f32x4*)&fnn[(size_t)(r0 + rl) * F + c4 * 4] = v;
    }
}

// ---- fallback: proven R4 monolithic kernel (used only if ws too small) ----
__global__ __launch_bounds__(256, 3) void nam_mono(
    const float* __restrict__ inputs, const float* __restrict__ W1,
    const float* __restrict__ b1, const float* __restrict__ W2,
    const float* __restrict__ b2, const float* __restrict__ W3,
    const float* __restrict__ b3, float* __restrict__ out,
    float* __restrict__ fnn_out)
{
    const int tid = threadIdx.x;
    const int f = blockIdx.y;
    const int b0 = blockIdx.x * 256;

    const float* W1f = W1 + f * H;
    const float* b1f = b1 + f * H;
    const float* W2f = W2 + (size_t)f * H * H;
    const float* b2f = b2 + f * H;
    const float* W3f = W3 + f * H;

    __shared__ __align__(16) short bhi_s[512 * 8];
    __shared__ __align__(16) short blo_s[512 * 8];

#pragma unroll
    for (int t = tid; t < 512; t += 256) {
        const int n = t & 63;
        const int g = t >> 6;
        const int nt = n >> 4, c = n & 15;
        const int ks = g >> 2, q = g & 3;
        const int slot = (nt * 2 + ks) * 64 + c + 16 * q;
        bf16x8 hv, lv;
#pragma unroll
        for (int jj = 0; jj < 8; ++jj) {
            const float wv = W2f[(g * 8 + jj) * H + n];
            const unsigned short hi = f32_to_bf16_rne(wv);
            const unsigned short lo = f32_to_bf16_rne(wv - bf16_to_f32(hi));
            hv[jj] = (short)hi;
            lv[jj] = (short)lo;
        }
        *(bf16x8*)&bhi_s[slot * 8] = hv;
        *(bf16x8*)&blo_s[slot * 8] = lv;
    }

    const int lane = tid & 63;
    const int w    = tid >> 6;
    const int q    = lane >> 4;
    const int col  = lane & 15;

    float w1v[16], b1v[16];
#pragma unroll
    for (int ks = 0; ks < 2; ++ks)
#pragma unroll
        for (int j = 0; j < 8; ++j) {
            w1v[ks * 8 + j] = W1f[ks * 32 + q * 8 + j];
            b1v[ks * 8 + j] = b1f[ks * 32 + q * 8 + j];
        }
    float b2v[4], w3v[4];
#pragma unroll
    for (int nt = 0; nt < 4; ++nt) {
        b2v[nt] = b2f[nt * 16 + col];
        w3v[nt] = W3f[nt * 16 + col];
    }
    const float b3f = b3[f];

    float x4[4];
#pragma unroll
    for (int mt = 0; mt < 4; ++mt)
        x4[mt] = inputs[(size_t)(b0 + w * 64 + mt * 16 + col) * F + f];

    __syncthreads();

    bf16x8 bhi[4][2], blo[4][2];
#pragma unroll
    for (int nt = 0; nt < 4; ++nt)
#pragma unroll
        for (int ks = 0; ks < 2; ++ks) {
            const int slot = (nt * 2 + ks) * 64 + lane;
            bhi[nt][ks] = *(bf16x8*)&bhi_s[slot * 8];
            blo[nt][ks] = *(bf16x8*)&blo_s[slot * 8];
        }

#pragma unroll 1
    for (int mt = 0; mt < 4; ++mt) {
        const int rbase = b0 + w * 64 + mt * 16;
        const float x = x4[mt];

        f32x4 acc[4];
#pragma unroll
        for (int nt = 0; nt < 4; ++nt) {
            acc[nt][0] = b2v[nt]; acc[nt][1] = b2v[nt];
            acc[nt][2] = b2v[nt]; acc[nt][3] = b2v[nt];
        }

#pragma unroll
        for (int ks = 0; ks < 2; ++ks) {
            union { unsigned int u[4]; bf16x8 v; } Ah, Al;
#pragma unroll
            for (int t = 0; t < 4; ++t) {
                const float r0 = fmaxf(fmaf(x, w1v[ks * 8 + 2 * t],     b1v[ks * 8 + 2 * t]),     0.0f);
                const float r1 = fmaxf(fmaf(x, w1v[ks * 8 + 2 * t + 1], b1v[ks * 8 + 2 * t + 1]), 0.0f);
                const unsigned int u0 = __float_as_uint(r0);
                const unsigned int u1 = __float_as_uint(r1);
                const float l0 = r0 - __uint_as_float(u0 & 0xFFFF0000u);
                const float l1 = r1 - __uint_as_float(u1 & 0xFFFF0000u);
                Ah.u[t] = __builtin_amdgcn_perm(u1, u0, 0x07060302);
                Al.u[t] = __builtin_amdgcn_perm(__float_as_uint(l1),
                                                __float_as_uint(l0), 0x07060302);
            }
#pragma unroll
            for (int nt = 0; nt < 4; ++nt) {
                acc[nt] = __builtin_amdgcn_mfma_f32_16x16x32_bf16(Ah.v, bhi[nt][ks], acc[nt], 0, 0, 0);
                acc[nt] = __builtin_amdgcn_mfma_f32_16x16x32_bf16(Ah.v, blo[nt][ks], acc[nt], 0, 0, 0);
                acc[nt] = __builtin_amdgcn_mfma_f32_16x16x32_bf16(Al.v, bhi[nt][ks], acc[nt], 0, 0, 0);
            }
        }

        float s[4];
#pragma unroll
        for (int reg = 0; reg < 4; ++reg) {
            float t = 0.0f;
#pragma unroll
            for (int nt = 0; nt < 4; ++nt)
                t = fmaf(fmaxf(acc[nt][reg], 0.0f), w3v[nt], t);
            s[reg] = t;
        }
#pragma unroll
        for (int m_ = 1; m_ <= 8; m_ <<= 1)
#pragma unroll
            for (int reg = 0; reg < 4; ++reg)
                s[reg] += __shfl_xor(s[reg], m_, 64);
        if (col == 0) {
#pragma unroll
            for (int reg = 0; reg < 4; ++reg) {
                const int row = rbase + 4 * q + reg;
                const float val = s[reg] + b3f;
                fnn_out[(size_t)row * F + f] = val;
                atomicAdd(&out[row], val);
            }
        }
    }
}

extern "C" void kernel_launch(void* const* d_in, const int* in_sizes, int n_in,
                              void* d_out, int out_size, void* d_ws, size_t ws_size,
                              hipStream_t stream) {
    const float* inputs = (const float*)d_in[0];
    const float* W1     = (const float*)d_in[1];
    const float* b1     = (const float*)d_in[2];
    const float* W2     = (const float*)d_in[3];
    const float* b2     = (const float*)d_in[4];
    const float* W3     = (const float*)d_in[5];
    const float* b3     = (const float*)d_in[6];

    float* out = (float*)d_out;   // (B,)
    float* fnn = out + B;         // (B, F)

    const size_t WS_NEEDED = (size_t)F * 4096 * 2 * sizeof(short)   // tables 2MB
                           + (size_t)F * B * sizeof(float);         // fnw 4MB

    if (ws_size >= WS_NEEDED) {
        short* bhi_g = (short*)d_ws;                        // 1 MB
        short* blo_g = bhi_g + (size_t)F * 4096;            // 1 MB
        float* fnw   = (float*)(blo_g + (size_t)F * 4096);  // 4 MB  (F, B)

        nam_prep<<<dim3(F), 256, 0, stream>>>(W2, bhi_g, blo_g);
        nam_main<<<dim3(B / 512, F), 256, 0, stream>>>(inputs, W1, b1, bhi_g,
                                                       blo_g, b2, W3, b3, fnw);
        nam_finish<<<dim3(128), 256, 0, stream>>>(fnw, fnn, out);
    } else {
        hipMemsetAsync(out, 0, B * sizeof(float), stream);
        nam_mono<<<dim3(B / 256, F), 256, 0, stream>>>(inputs, W1, b1, W2, b2,
                                                       W3, b3, out, fnn);
    }
}

// Round 9
// 99.234 us; speedup vs baseline: 2.0498x; 1.0009x over previous
//
#include <hip/hip_runtime.h>

#define B 8192
#define F 128
#define H 64

typedef __attribute__((ext_vector_type(8))) short bf16x8;
typedef __attribute__((ext_vector_type(4))) float f32x4;

static __device__ __forceinline__ unsigned short f32_to_bf16_rne(float v) {
    unsigned int u = __float_as_uint(v);
    unsigned int r = (u + 0x7FFFu + ((u >> 16) & 1u)) >> 16;
    return (unsigned short)r;
}
static __device__ __forceinline__ float bf16_to_f32(unsigned short h) {
    return __uint_as_float(((unsigned int)h) << 16);
}

// global->LDS DMA; LDS dest is wave-uniform base + lane*size (linear);
// global src is PER-LANE (strided gathers allowed).
#define GLOAD_LDS16(gp, lp)                                                  \
    __builtin_amdgcn_global_load_lds(                                        \
        (const __attribute__((address_space(1))) unsigned int*)(gp),         \
        (__attribute__((address_space(3))) unsigned int*)(lp), 16, 0, 0)
#define GLOAD_LDS4(gp, lp)                                                   \
    __builtin_amdgcn_global_load_lds(                                        \
        (const __attribute__((address_space(1))) unsigned int*)(gp),         \
        (__attribute__((address_space(3))) unsigned int*)(lp), 4, 0, 0)

// Split-bf16 MFMA NAM.  Layer2 = 3x mfma_f32_16x16x32_bf16 (hh + hl + lh).
// R13: R12 (unroll 2) gained only ~1us.  Refined model: under (256,3) the
// VGPR allocator cap is ~85 (evidence: (256,4) forced 64, (256,3) gives
// exactly 80), so unroll-2 couldn't keep a 2nd acc-set live -> deeper
// unroll is dead under this bound.  Remaining stall: main ~4.1us/block-slot
// vs ~0.9us issue work (~75% stall, correlated across lockstep waves --
// why R11's occupancy bump did nothing).  The only long-latency op left in
// the mt loop is the x-gather (64 lanes x 4B @ 512B stride, L2/L3 latency
// 300-900cyc, prefetch distance one mt body ~300cyc).  Single change:
// stage each wave's 128 x values into LDS via TWO global_load_lds size-4
// DMAs (per-lane strided src, linear lane*4 dest) issued with the table
// DMA, drained by the existing __syncthreads.  The mt loop now has ZERO
// global loads; x becomes a conflict-free ds_read_b32 (16 addrs x 4-lane
// multicast).  Same bits, same traffic -> absmax unchanged.
// Hard rules kept: __launch_bounds__(256,3) ONLY ((256,4) -> 64-VGPR spill
// catastrophe, twice measured); LDS table via global_load_lds (linear
// dest); grid (16,F); fire-and-forget LDS scatter epilogue + per-half
// reduce (no shfl chains); ws guard + R4-mono fallback; no memset in
// fast path.

// ---- prep: F blocks: W2 (H,H) f32 -> hi/lo bf16 B-fragment table ----
__global__ __launch_bounds__(256) void nam_prep(
    const float* __restrict__ W2, short* __restrict__ bhi_g,
    short* __restrict__ blo_g)
{
    const int tid = threadIdx.x;
    const int f = blockIdx.x;
    const float* W2f = W2 + (size_t)f * H * H;
    short* bhi = bhi_g + (size_t)f * 4096;
    short* blo = blo_g + (size_t)f * 4096;
#pragma unroll
    for (int t = tid; t < 512; t += 256) {
        const int n = t & 63;          // output hidden index (MFMA n)
        const int g = t >> 6;          // h-group: h = g*8 + jj (MFMA k)
        const int nt = n >> 4, c = n & 15;
        const int ks = g >> 2, q = g & 3;
        const int slot = (nt * 2 + ks) * 64 + c + 16 * q;
        bf16x8 hv, lv;
#pragma unroll
        for (int jj = 0; jj < 8; ++jj) {
            const float wv = W2f[(g * 8 + jj) * H + n];
            const unsigned short hi = f32_to_bf16_rne(wv);
            const unsigned short lo = f32_to_bf16_rne(wv - bf16_to_f32(hi));
            hv[jj] = (short)hi;
            lv[jj] = (short)lo;
        }
        *(bf16x8*)&bhi[slot * 8] = hv;
        *(bf16x8*)&blo[slot * 8] = lv;
    }
}

__global__ __launch_bounds__(256, 3) void nam_main(
    const float* __restrict__ inputs, const float* __restrict__ W1,
    const float* __restrict__ b1, const short* __restrict__ bhi_g,
    const short* __restrict__ blo_g, const float* __restrict__ b2,
    const float* __restrict__ W3, const float* __restrict__ b3,
    float* __restrict__ fnn_ws)
{
    const int tid = threadIdx.x;
    const int f = blockIdx.y;
    const int b0 = blockIdx.x * 512;   // 512 rows per block

    const int lane = tid & 63;
    const int w    = tid >> 6;
    const int q    = lane >> 4;   // quad
    const int col  = lane & 15;

    // per-wave partial-sum tile, 64 rows: row = (mt&3)*16+4q+reg, 16 cols,
    // pad to 18 f32 -> <=2-way bank aliasing (free).  Reduced after mt=3/7.
    __shared__ float s_tile[4][64][18];         // 18432 B
    __shared__ __align__(16) short bhs[4096];   // 8 KB
    __shared__ __align__(16) short bls[4096];   // 8 KB
    __shared__ float x_lds[4][128];             // 2 KB: per-wave x values

    // ---- DMA: table slice (16KB) + this wave's 128 x values, one drain ----
    {
        const short* bhi_f = bhi_g + (size_t)f * 4096;
        const short* blo_f = blo_g + (size_t)f * 4096;
#pragma unroll
        for (int c = w; c < 8; c += 4) {      // 2 chunks/table/wave
            GLOAD_LDS16(bhi_f + c * 512 + lane * 8, &bhs[c * 512]);
            GLOAD_LDS16(blo_f + c * 512 + lane * 8, &bls[c * 512]);
        }
        // x stage: rows [b0 + w*128, +128), strided 512B per-lane src,
        // linear lane*4 LDS dest.  Same addresses/bits as the old per-mt
        // gathers (L2/L3-absorbed, R0-proven).
        GLOAD_LDS4(inputs + (size_t)(b0 + w * 128 + lane) * F + f,
                   &x_lds[w][0]);
        GLOAD_LDS4(inputs + (size_t)(b0 + w * 128 + 64 + lane) * F + f,
                   &x_lds[w][64]);
    }

    // per-lane weight vectors (L2-hot broadcasts; overlap with DMA)
    const float* W1f = W1 + f * H;
    const float* b1f = b1 + f * H;
    float w1v[16], b1v[16];
#pragma unroll
    for (int ks = 0; ks < 2; ++ks)
#pragma unroll
        for (int j = 0; j < 8; ++j) {
            w1v[ks * 8 + j] = W1f[ks * 32 + q * 8 + j];
            b1v[ks * 8 + j] = b1f[ks * 32 + q * 8 + j];
        }
    const float* b2f = b2 + f * H;
    const float* W3f = W3 + f * H;
    float b2v[4], w3v[4];
#pragma unroll
    for (int nt = 0; nt < 4; ++nt) {
        b2v[nt] = b2f[nt * 16 + col];
        w3v[nt] = W3f[nt * 16 + col];
    }
    const float b3f = b3[f];

    __syncthreads();   // drains table DMA + x DMA together

    // ---- resident B fragments (LDS -> regs, once per block) ----
    bf16x8 bhi[4][2], blo[4][2];
#pragma unroll
    for (int nt = 0; nt < 4; ++nt)
#pragma unroll
        for (int ks = 0; ks < 2; ++ks) {
            const int slot = (nt * 2 + ks) * 64 + lane;
            bhi[nt][ks] = *(bf16x8*)&bhs[slot * 8];
            blo[nt][ks] = *(bf16x8*)&bls[slot * 8];
        }

    // ---- 8 m-tiles of 16 rows per wave; ZERO global loads in loop ----
#pragma unroll 2
    for (int mt = 0; mt < 8; ++mt) {
        // x via LDS: 16 addrs x 4-lane same-address multicast, conflict-free
        const float x = x_lds[w][(mt << 4) | col];

        f32x4 acc[4];
#pragma unroll
        for (int nt = 0; nt < 4; ++nt) {
            acc[nt][0] = b2v[nt]; acc[nt][1] = b2v[nt];
            acc[nt][2] = b2v[nt]; acc[nt][3] = b2v[nt];
        }

#pragma unroll
        for (int ks = 0; ks < 2; ++ks) {
            // A-frag: trunc-Dekker split, v_perm pair-packing.
            union { unsigned int u[4]; bf16x8 v; } Ah, Al;
#pragma unroll
            for (int t = 0; t < 4; ++t) {
                const float r0 = fmaxf(fmaf(x, w1v[ks * 8 + 2 * t],     b1v[ks * 8 + 2 * t]),     0.0f);
                const float r1 = fmaxf(fmaf(x, w1v[ks * 8 + 2 * t + 1], b1v[ks * 8 + 2 * t + 1]), 0.0f);
                const unsigned int u0 = __float_as_uint(r0);
                const unsigned int u1 = __float_as_uint(r1);
                const float l0 = r0 - __uint_as_float(u0 & 0xFFFF0000u);
                const float l1 = r1 - __uint_as_float(u1 & 0xFFFF0000u);
                Ah.u[t] = __builtin_amdgcn_perm(u1, u0, 0x07060302);
                Al.u[t] = __builtin_amdgcn_perm(__float_as_uint(l1),
                                                __float_as_uint(l0), 0x07060302);
            }
#pragma unroll
            for (int nt = 0; nt < 4; ++nt) {
                acc[nt] = __builtin_amdgcn_mfma_f32_16x16x32_bf16(Ah.v, bhi[nt][ks], acc[nt], 0, 0, 0);
                acc[nt] = __builtin_amdgcn_mfma_f32_16x16x32_bf16(Ah.v, blo[nt][ks], acc[nt], 0, 0, 0);
                acc[nt] = __builtin_amdgcn_mfma_f32_16x16x32_bf16(Al.v, bhi[nt][ks], acc[nt], 0, 0, 0);
            }
        }

        // ---- epilogue: fold W3 and scatter partials (fire-and-forget) ----
#pragma unroll
        for (int reg = 0; reg < 4; ++reg) {
            float t = 0.0f;
#pragma unroll
            for (int nt = 0; nt < 4; ++nt)
                t = fmaf(fmaxf(acc[nt][reg], 0.0f), w3v[nt], t);
            s_tile[w][(mt & 3) * 16 + 4 * q + reg][col] = t;
        }

        // ---- per-half reduce: 64 rows, 1 row/lane; coalesced 256B store ----
        if ((mt & 3) == 3) {
            float sum = 0.0f;
#pragma unroll
            for (int c = 0; c < 16; ++c)
                sum += s_tile[w][lane][c];
            float* dst = fnn_ws + (size_t)f * B + b0 + w * 128 + (mt >> 2) * 64;
            dst[lane] = sum + b3f;
        }
    }
}

// ---- finish: fnn_ws (F,B) -> fnn (B,F) transpose + out row-sums ----
// 128 blocks, each handles 64 rows x all 128 features: 'out' needs no
// atomics (full sum local to block) and no prior memset.
__global__ __launch_bounds__(256) void nam_finish(
    const float* __restrict__ fnn_ws, float* __restrict__ fnn,
    float* __restrict__ out)
{
    const int tid = threadIdx.x;
    const int r0 = blockIdx.x * 64;
    __shared__ float tile[128][65];    // 33280 B
    __shared__ float psum[4][64];

    float rsum = 0.0f;
#pragma unroll
    for (int j = 0; j < 32; ++j) {     // coalesced 256B/64-lane reads
        const int fl = j * 4 + (tid >> 6);
        const int rl = tid & 63;
        const float v = fnn_ws[(size_t)fl * B + r0 + rl];
        tile[fl][rl] = v;
        rsum += v;
    }
    psum[tid >> 6][tid & 63] = rsum;
    __syncthreads();
    if (tid < 64)                      // plain store; no atomic, no memset
        out[r0 + tid] = psum[0][tid] + psum[1][tid] + psum[2][tid] + psum[3][tid];

#pragma unroll
    for (int j = 0; j < 8; ++j) {      // fnn rows: 512B-contiguous float4 writes
        const int rl = j * 8 + (tid >> 5);
        const int c4 = tid & 31;
        f32x4 v;
        v[0] = tile[c4 * 4 + 0][rl];
        v[1] = tile[c4 * 4 + 1][rl];
        v[2] = tile[c4 * 4 + 2][rl];
        v[3] = tile[c4 * 4 + 3][rl];
        *(f32x4*)&fnn[(size_t)(r0 + rl) * F + c4 * 4] = v;
    }
}

// ---- fallback: proven R4 monolithic kernel (used only if ws too small) ----
__global__ __launch_bounds__(256, 3) void nam_mono(
    const float* __restrict__ inputs, const float* __restrict__ W1,
    const float* __restrict__ b1, const float* __restrict__ W2,
    const float* __restrict__ b2, const float* __restrict__ W3,
    const float* __restrict__ b3, float* __restrict__ out,
    float* __restrict__ fnn_out)
{
    const int tid = threadIdx.x;
    const int f = blockIdx.y;
    const int b0 = blockIdx.x * 256;

    const float* W1f = W1 + f * H;
    const float* b1f = b1 + f * H;
    const float* W2f = W2 + (size_t)f * H * H;
    const float* b2f = b2 + f * H;
    const float* W3f = W3 + f * H;

    __shared__ __align__(16) short bhi_s[512 * 8];
    __shared__ __align__(16) short blo_s[512 * 8];

#pragma unroll
    for (int t = tid; t < 512; t += 256) {
        const int n = t & 63;
        const int g = t >> 6;
        const int nt = n >> 4, c = n & 15;
        const int ks = g >> 2, q = g & 3;
        const int slot = (nt * 2 + ks) * 64 + c + 16 * q;
        bf16x8 hv, lv;
#pragma unroll
        for (int jj = 0; jj < 8; ++jj) {
            const float wv = W2f[(g * 8 + jj) * H + n];
            const unsigned short hi = f32_to_bf16_rne(wv);
            const unsigned short lo = f32_to_bf16_rne(wv - bf16_to_f32(hi));
            hv[jj] = (short)hi;
            lv[jj] = (short)lo;
        }
        *(bf16x8*)&bhi_s[slot * 8] = hv;
        *(bf16x8*)&blo_s[slot * 8] = lv;
    }

    const int lane = tid & 63;
    const int w    = tid >> 6;
    const int q    = lane >> 4;
    const int col  = lane & 15;

    float w1v[16], b1v[16];
#pragma unroll
    for (int ks = 0; ks < 2; ++ks)
#pragma unroll
        for (int j = 0; j < 8; ++j) {
            w1v[ks * 8 + j] = W1f[ks * 32 + q * 8 + j];
            b1v[ks * 8 + j] = b1f[ks * 32 + q * 8 + j];
        }
    float b2v[4], w3v[4];
#pragma unroll
    for (int nt = 0; nt < 4; ++nt) {
        b2v[nt] = b2f[nt * 16 + col];
        w3v[nt] = W3f[nt * 16 + col];
    }
    const float b3f = b3[f];

    float x4[4];
#pragma unroll
    for (int mt = 0; mt < 4; ++mt)
        x4[mt] = inputs[(size_t)(b0 + w * 64 + mt * 16 + col) * F + f];

    __syncthreads();

    bf16x8 bhi[4][2], blo[4][2];
#pragma unroll
    for (int nt = 0; nt < 4; ++nt)
#pragma unroll
        for (int ks = 0; ks < 2; ++ks) {
            const int slot = (nt * 2 + ks) * 64 + lane;
            bhi[nt][ks] = *(bf16x8*)&bhi_s[slot * 8];
            blo[nt][ks] = *(bf16x8*)&blo_s[slot * 8];
        }

#pragma unroll 1
    for (int mt = 0; mt < 4; ++mt) {
        const int rbase = b0 + w * 64 + mt * 16;
        const float x = x4[mt];

        f32x4 acc[4];
#pragma unroll
        for (int nt = 0; nt < 4; ++nt) {
            acc[nt][0] = b2v[nt]; acc[nt][1] = b2v[nt];
            acc[nt][2] = b2v[nt]; acc[nt][3] = b2v[nt];
        }

#pragma unroll
        for (int ks = 0; ks < 2; ++ks) {
            union { unsigned int u[4]; bf16x8 v; } Ah, Al;
#pragma unroll
            for (int t = 0; t < 4; ++t) {
                const float r0 = fmaxf(fmaf(x, w1v[ks * 8 + 2 * t],     b1v[ks * 8 + 2 * t]),     0.0f);
                const float r1 = fmaxf(fmaf(x, w1v[ks * 8 + 2 * t + 1], b1v[ks * 8 + 2 * t + 1]), 0.0f);
                const unsigned int u0 = __float_as_uint(r0);
                const unsigned int u1 = __float_as_uint(r1);
                const float l0 = r0 - __uint_as_float(u0 & 0xFFFF0000u);
                const float l1 = r1 - __uint_as_float(u1 & 0xFFFF0000u);
                Ah.u[t] = __builtin_amdgcn_perm(u1, u0, 0x07060302);
                Al.u[t] = __builtin_amdgcn_perm(__float_as_uint(l1),
                                                __float_as_uint(l0), 0x07060302);
            }
#pragma unroll
            for (int nt = 0; nt < 4; ++nt) {
                acc[nt] = __builtin_amdgcn_mfma_f32_16x16x32_bf16(Ah.v, bhi[nt][ks], acc[nt], 0, 0, 0);
                acc[nt] = __builtin_amdgcn_mfma_f32_16x16x32_bf16(Ah.v, blo[nt][ks], acc[nt], 0, 0, 0);
                acc[nt] = __builtin_amdgcn_mfma_f32_16x16x32_bf16(Al.v, bhi[nt][ks], acc[nt], 0, 0, 0);
            }
        }

        float s[4];
#pragma unroll
        for (int reg = 0; reg < 4; ++reg) {
            float t = 0.0f;
#pragma unroll
            for (int nt = 0; nt < 4; ++nt)
                t = fmaf(fmaxf(acc[nt][reg], 0.0f), w3v[nt], t);
            s[reg] = t;
        }
#pragma unroll
        for (int m_ = 1; m_ <= 8; m_ <<= 1)
#pragma unroll
            for (int reg = 0; reg < 4; ++reg)
                s[reg] += __shfl_xor(s[reg], m_, 64);
        if (col == 0) {
#pragma unroll
            for (int reg = 0; reg < 4; ++reg) {
                const int row = rbase + 4 * q + reg;
                const float val = s[reg] + b3f;
                fnn_out[(size_t)row * F + f] = val;
                atomicAdd(&out[row], val);
            }
        }
    }
}

extern "C" void kernel_launch(void* const* d_in, const int* in_sizes, int n_in,
                              void* d_out, int out_size, void* d_ws, size_t ws_size,
                              hipStream_t stream) {
    const float* inputs = (const float*)d_in[0];
    const float* W1     = (const float*)d_in[1];
    const float* b1     = (const float*)d_in[2];
    const float* W2     = (const float*)d_in[3];
    const float* b2     = (const float*)d_in[4];
    const float* W3     = (const float*)d_in[5];
    const float* b3     = (const float*)d_in[6];

    float* out = (float*)d_out;   // (B,)
    float* fnn = out + B;         // (B, F)

    const size_t WS_NEEDED = (size_t)F * 4096 * 2 * sizeof(short)   // tables 2MB
                           + (size_t)F * B * sizeof(float);         // fnw 4MB

    if (ws_size >= WS_NEEDED) {
        short* bhi_g = (short*)d_ws;                        // 1 MB
        short* blo_g = bhi_g + (size_t)F * 4096;            // 1 MB
        float* fnw   = (float*)(blo_g + (size_t)F * 4096);  // 4 MB  (F, B)

        nam_prep<<<dim3(F), 256, 0, stream>>>(W2, bhi_g, blo_g);
        nam_main<<<dim3(B / 512, F), 256, 0, stream>>>(inputs, W1, b1, bhi_g,
                                                       blo_g, b2, W3, b3, fnw);
        nam_finish<<<dim3(128), 256, 0, stream>>>(fnw, fnn, out);
    } else {
        hipMemsetAsync(out, 0, B * sizeof(float), stream);
        nam_mono<<<dim3(B / 256, F), 256, 0, stream>>>(inputs, W1, b1, W2, b2,
                                                       W3, b3, out, fnn);
    }
}